// Round 1
// baseline (2087.462 us; speedup 1.0000x reference)
//
#include <hip/hip_runtime.h>
#include <cstddef>

#define NN 8192
#define FD 768
#define HIDD 384
#define NNZE 131072
#define DCATD 1536

typedef short bf16x8 __attribute__((ext_vector_type(8)));
typedef float f32x4 __attribute__((ext_vector_type(4)));

__device__ __forceinline__ short f2bf(float f){
  unsigned u = __float_as_uint(f);
  unsigned r = u + 0x7FFFu + ((u>>16)&1u);   // RNE
  return (short)(r>>16);
}
__device__ __forceinline__ unsigned fmapu(float f){
  unsigned u = __float_as_uint(f);
  return (u & 0x80000000u) ? ~u : (u | 0x80000000u);
}
__device__ __forceinline__ float funmapu(unsigned m){
  unsigned u = (m & 0x80000000u) ? (m & 0x7FFFFFFFu) : ~m;
  return __uint_as_float(u);
}

// ---------------- CSR build ----------------
__global__ void k_hist(const int* __restrict__ row, const int* __restrict__ col,
                       int* __restrict__ cr, int* __restrict__ cc){
  int e = blockIdx.x*256 + threadIdx.x;
  if(e >= NNZE) return;
  atomicAdd(&cc[col[e]], 1);
  atomicAdd(&cr[row[e]], 1);
}

__global__ __launch_bounds__(1024) void k_scan8192(const int* __restrict__ cnt,
                                                   int* __restrict__ offs, int* __restrict__ cur){
  __shared__ int part[1024];
  int t = threadIdx.x;
  int v[8]; int s = 0;
  #pragma unroll
  for(int j=0;j<8;j++){ v[j]=cnt[t*8+j]; s+=v[j]; }
  part[t]=s; __syncthreads();
  for(int d=1; d<1024; d<<=1){
    int mine = part[t];
    int add = (t>=d)? part[t-d] : 0;
    __syncthreads();
    part[t] = mine + add;
    __syncthreads();
  }
  int excl = part[t]-s;
  #pragma unroll
  for(int j=0;j<8;j++){ offs[t*8+j]=excl; cur[t*8+j]=excl; excl+=v[j]; }
  if(t==1023) offs[8192]=excl;
}

__global__ void k_scatter(const int* __restrict__ row, const int* __restrict__ col,
                          int* __restrict__ ccur, int* __restrict__ rcur,
                          int* __restrict__ ceids, int* __restrict__ reids){
  int e = blockIdx.x*256 + threadIdx.x;
  if(e >= NNZE) return;
  int p = atomicAdd(&ccur[col[e]],1); ceids[p]=e;
  int q = atomicAdd(&rcur[row[e]],1); reids[q]=e;
}

__global__ void k_deg(const int* __restrict__ cc, const int* __restrict__ cr,
                      float* __restrict__ Bn, float* __restrict__ Dn){
  int i = blockIdx.x*256 + threadIdx.x;
  if(i>=NN) return;
  int c=cc[i]; Bn[i] = c>0 ? 1.f/(float)c : 0.f;
  int r=cr[i]; Dn[i] = r>0 ? 1.f/(float)r : 0.f;
}

// ---------------- GraphNorm ----------------
__global__ __launch_bounds__(256) void k_colstats(const float* __restrict__ src,
                                                  float* __restrict__ gs, float* __restrict__ gss){
  int col = blockIdx.x*256 + threadIdx.x;     // 0..767
  int r0 = blockIdx.y*256;
  float s1=0.f, s2=0.f;
  for(int r=0;r<256;r++){
    float v = src[(size_t)(r0+r)*FD + col];
    s1+=v; s2+=v*v;
  }
  atomicAdd(&gs[col], s1);
  atomicAdd(&gss[col], s2);
}

__global__ void k_gn_fin(const float* __restrict__ gs, const float* __restrict__ gss,
                         const float* __restrict__ w_, const float* __restrict__ b_,
                         const float* __restrict__ ms_, float* __restrict__ A, float* __restrict__ B){
  int c = blockIdx.x*256 + threadIdx.x;
  if(c>=FD) return;
  float mean = gs[c]*(1.f/(float)NN);
  float ex2  = gss[c]*(1.f/(float)NN);
  float ctr  = ms_[c]*mean;
  float var  = ex2 - 2.f*ctr*mean + ctr*ctr;
  float a    = w_[c] / sqrtf(var + 1e-5f);
  A[c]=a; B[c]=b_[c] - a*ctr;
}

// ---------------- casts ----------------
__global__ void k_cast_bf16(const float* __restrict__ s, short* __restrict__ d, int n){
  int i = blockIdx.x*256+threadIdx.x;
  if(i<n) d[i]=f2bf(s[i]);
}
__global__ void k_affcast(const float* __restrict__ s, const float* __restrict__ A,
                          const float* __restrict__ B, short* __restrict__ d){
  int i = blockIdx.x*256+threadIdx.x;   // NN*FD total
  if(i>=NN*FD) return;
  int c = i - (i/FD)*FD;
  d[i] = f2bf(A[c]*s[i] + B[c]);
}

// ---------------- bf16 NT GEMM: C[M,N] = A[M,K] @ B[N,K]^T (+bias, lrelu) ----------------
__global__ __launch_bounds__(256) void gemm_nt(const short* __restrict__ A, const short* __restrict__ B,
    float* __restrict__ C, int M, int N, int K,
    const float* __restrict__ bias, float slope){
  int lane = threadIdx.x & 63;
  int wv   = threadIdx.x >> 6;
  int m0 = (blockIdx.y*4 + wv)*64;
  int n0 = blockIdx.x*64;
  int li = lane & 15, q = lane >> 4;
  const short* Ab = A + (size_t)(m0+li)*K + q*8;
  const short* Bb = B + (size_t)(n0+li)*K + q*8;
  f32x4 acc[4][4];
  #pragma unroll
  for(int i=0;i<4;i++)
    #pragma unroll
    for(int j=0;j<4;j++) acc[i][j] = (f32x4){0.f,0.f,0.f,0.f};
  for(int k0=0;k0<K;k0+=32){
    bf16x8 a[4], b[4];
    #pragma unroll
    for(int i=0;i<4;i++) a[i] = *(const bf16x8*)(Ab + (size_t)i*16*K + k0);
    #pragma unroll
    for(int j=0;j<4;j++) b[j] = *(const bf16x8*)(Bb + (size_t)j*16*K + k0);
    #pragma unroll
    for(int i=0;i<4;i++)
      #pragma unroll
      for(int j=0;j<4;j++)
        acc[i][j] = __builtin_amdgcn_mfma_f32_16x16x32_bf16(a[i], b[j], acc[i][j], 0, 0, 0);
  }
  #pragma unroll
  for(int i=0;i<4;i++){
    int gm = m0 + i*16 + q*4;
    #pragma unroll
    for(int j=0;j<4;j++){
      int gn = n0 + j*16 + li;
      float bv = bias ? bias[gn] : 0.f;
      #pragma unroll
      for(int r=0;r<4;r++){
        float vv = acc[i][j][r] + bv;
        vv = (vv>=0.f) ? vv : vv*slope;
        C[(size_t)(gm+r)*N + gn] = vv;
      }
    }
  }
}

// ---------------- watt: wx[c]=gnA[c]*sum_f W[f,c]*att[f]; we[c]=sum_f W[f,c]*att[FD+f];
//                  aconst += gnB[c]*sum_f W[f,c]*att[f] ----------------
__global__ __launch_bounds__(256) void k_watt(const float* __restrict__ W, const float* __restrict__ att,
    const float* __restrict__ gnA, const float* __restrict__ gnB,
    float* __restrict__ wx, float* __restrict__ we, float* __restrict__ aconst){
  int c = blockIdx.x; int t = threadIdx.x;
  float sA=0.f, sB=0.f;
  for(int f=t; f<FD; f+=256){
    float w = W[(size_t)f*FD + c];
    sA += w*att[f];
    sB += w*att[FD+f];
  }
  __shared__ float shA[256], shB[256];
  shA[t]=sA; shB[t]=sB; __syncthreads();
  for(int s=128;s>0;s>>=1){ if(t<s){ shA[t]+=shA[t+s]; shB[t]+=shB[t+s]; } __syncthreads(); }
  if(t==0){ float a=shA[0]; wx[c]=gnA[c]*a; we[c]=shB[0]; atomicAdd(aconst, gnB[c]*a); }
}

// a[i] = sum_c src[i,c]*wv[c] (+ cst)
__global__ __launch_bounds__(64) void k_matvec(const float* __restrict__ src, const float* __restrict__ wv,
    const float* __restrict__ cst, float* __restrict__ out){
  int i = blockIdx.x, l = threadIdx.x;
  float s=0.f;
  for(int c=l;c<FD;c+=64) s += src[(size_t)i*FD+c]*wv[c];
  for(int o=32;o;o>>=1) s += __shfl_down(s,o);
  if(l==0) out[i] = s + (cst ? cst[0] : 0.f);
}

// ---------------- alpha / segment softmax ----------------
__global__ void k_alpha1(const int* __restrict__ row, const int* __restrict__ col,
                         const float* __restrict__ ax, const float* __restrict__ ae,
                         float* __restrict__ araw, unsigned* __restrict__ segmax){
  int e = blockIdx.x*256 + threadIdx.x;
  if(e>=NNZE) return;
  float a = ax[row[e]] + ae[col[e]];
  a = (a>=0.f) ? a : 0.2f*a;
  araw[e]=a;
  atomicMax(&segmax[col[e]], fmapu(a));
}
__global__ void k_alpha2(const int* __restrict__ col, const float* __restrict__ araw,
                         const unsigned* __restrict__ segmax,
                         float* __restrict__ eexp, float* __restrict__ esum){
  int e = blockIdx.x*256 + threadIdx.x;
  if(e>=NNZE) return;
  float m = funmapu(segmax[col[e]]);
  float x = expf(araw[e]-m);
  eexp[e]=x;
  atomicAdd(&esum[col[e]], x);
}
__global__ void k_alpha3(const int* __restrict__ col, const float* __restrict__ eexp,
                         const float* __restrict__ esum, float* __restrict__ asm_){
  int e = blockIdx.x*256 + threadIdx.x;
  if(e>=NNZE) return;
  asm_[e] = eexp[e] / (esum[col[e]] + 1e-16f);
}

// ---------------- segment gather-sum over 768-wide rows ----------------
__global__ __launch_bounds__(256) void k_seg_gather(const float* __restrict__ src,
    const int* __restrict__ offs, const int* __restrict__ eids,
    const int* __restrict__ gidx, const float* __restrict__ alpha_sm,
    const float* __restrict__ segscale, const float* __restrict__ bias, float slope,
    float* __restrict__ dst){
  int c = blockIdx.x, t = threadIdx.x;
  int beg = offs[c], end = offs[c+1];
  float scale = segscale[c];
  __shared__ float wsh[256]; __shared__ int rsh[256];
  float a0=0.f,a1=0.f,a2=0.f;
  for(int base=beg; base<end; base+=256){
    int idx = base+t;
    if(idx<end){ int e=eids[idx]; wsh[t]=alpha_sm[e]; rsh[t]=gidx[e]; }
    __syncthreads();
    int cnt = min(256, end-base);
    for(int j=0;j<cnt;j++){
      float wj = wsh[j];
      const float* r = src + (size_t)rsh[j]*FD;
      a0 += wj*r[t]; a1 += wj*r[t+256]; a2 += wj*r[t+512];
    }
    __syncthreads();
  }
  a0*=scale; a1*=scale; a2*=scale;
  if(bias){
    a0+=bias[t]; a1+=bias[t+256]; a2+=bias[t+512];
    a0=(a0>=0.f)?a0:slope*a0; a1=(a1>=0.f)?a1:slope*a1; a2=(a2>=0.f)?a2:slope*a2;
  }
  dst[(size_t)c*FD+t]=a0; dst[(size_t)c*FD+t+256]=a1; dst[(size_t)c*FD+t+512]=a2;
}

// ---------------- catT build: catT[d, i] = cat[i, d] in bf16 ----------------
__global__ __launch_bounds__(256) void k_build_catT(const float* __restrict__ x,
    const float* __restrict__ o1, const float* __restrict__ o2, short* __restrict__ catT){
  __shared__ float tile[32][33];
  int i0 = blockIdx.x*32, d0 = blockIdx.y*32;
  int tx = threadIdx.x, ty = threadIdx.y;   // 32 x 8
  const float* src; int dof, ld;
  if(d0 < FD){ src=x; dof=d0; ld=FD; }
  else if(d0 < FD+HIDD){ src=o1; dof=d0-FD; ld=HIDD; }
  else { src=o2; dof=d0-FD-HIDD; ld=HIDD; }
  for(int yy=ty; yy<32; yy+=8)
    tile[yy][tx] = src[(size_t)(i0+yy)*ld + dof + tx];
  __syncthreads();
  for(int yy=ty; yy<32; yy+=8)
    catT[(size_t)(d0+yy)*NN + i0 + tx] = f2bf(tile[tx][yy]);
}

// ---------------- attention mega-GEMM, fused relu*W2 reduction ----------------
__global__ __launch_bounds__(256) void attn_gemm(const short* __restrict__ catT,
    const float* __restrict__ W1, const float* __restrict__ b1, const float* __restrict__ W2,
    float* __restrict__ score_pre){
  const int K = NN;
  int lane = threadIdx.x & 63;
  int wv   = threadIdx.x >> 6;
  int m0 = (blockIdx.x*4 + wv)*64;   // DCAT tiles (6 blocks in x)
  int n0 = blockIdx.y*64;            // 128 blocks in y
  int li = lane & 15, q = lane >> 4;
  const short* Ab = catT + (size_t)(m0+li)*K + q*8;
  const float* Bb = W1 + (size_t)(n0+li)*K + q*8;
  f32x4 acc[4][4];
  #pragma unroll
  for(int i=0;i<4;i++)
    #pragma unroll
    for(int j=0;j<4;j++) acc[i][j] = (f32x4){0.f,0.f,0.f,0.f};
  for(int k0=0;k0<K;k0+=32){
    bf16x8 a[4], b[4];
    #pragma unroll
    for(int i=0;i<4;i++) a[i] = *(const bf16x8*)(Ab + (size_t)i*16*K + k0);
    #pragma unroll
    for(int j=0;j<4;j++){
      const float* p = Bb + (size_t)j*16*K + k0;
      float4 f0 = *(const float4*)p;
      float4 f1 = *(const float4*)(p+4);
      bf16x8 t;
      t[0]=f2bf(f0.x); t[1]=f2bf(f0.y); t[2]=f2bf(f0.z); t[3]=f2bf(f0.w);
      t[4]=f2bf(f1.x); t[5]=f2bf(f1.y); t[6]=f2bf(f1.z); t[7]=f2bf(f1.w);
      b[j]=t;
    }
    #pragma unroll
    for(int i=0;i<4;i++)
      #pragma unroll
      for(int j=0;j<4;j++)
        acc[i][j] = __builtin_amdgcn_mfma_f32_16x16x32_bf16(a[i], b[j], acc[i][j], 0, 0, 0);
  }
  float w2v[4], b1v[4];
  #pragma unroll
  for(int j=0;j<4;j++){ int gn=n0+j*16+li; w2v[j]=W2[gn]; b1v[j]=b1[gn]; }
  #pragma unroll
  for(int i=0;i<4;i++){
    #pragma unroll
    for(int r=0;r<4;r++){
      float s=0.f;
      #pragma unroll
      for(int j=0;j<4;j++){
        float v = acc[i][j][r] + b1v[j];
        v = v>0.f ? v : 0.f;
        s += v*w2v[j];
      }
      s += __shfl_xor(s,1); s += __shfl_xor(s,2); s += __shfl_xor(s,4); s += __shfl_xor(s,8);
      if(li==0) atomicAdd(&score_pre[m0 + i*16 + q*4 + r], s);
    }
  }
}

// ---------------- score finalize: sw[d][o] = (sigmoid(pre+b2)-center[d]) * cls_W[o][d] ----------------
__global__ void k_score(const float* __restrict__ pre, const float* __restrict__ b2,
                        const float* __restrict__ center, const float* __restrict__ clsW,
                        float* __restrict__ sw){
  int d = blockIdx.x*256 + threadIdx.x;
  if(d>=DCATD) return;
  float sc = pre[d] + b2[0];
  sc = 1.f/(1.f+expf(-sc));
  sc -= center[d];
  #pragma unroll
  for(int o=0;o<10;o++) sw[d*10+o] = sc * clsW[(size_t)o*DCATD + d];
}

// ---------------- final: out[i][o] = sum_d cat[i,d]*sw[d][o] + cls_b[o] ----------------
__global__ __launch_bounds__(64) void k_final(const float* __restrict__ x, const float* __restrict__ o1,
    const float* __restrict__ o2, const float* __restrict__ sw, const float* __restrict__ clsb,
    float* __restrict__ out){
  int i = blockIdx.x, l = threadIdx.x;
  float acc[10];
  #pragma unroll
  for(int o=0;o<10;o++) acc[o]=0.f;
  for(int d=l; d<DCATD; d+=64){
    float v = (d<FD) ? x[(size_t)i*FD + d]
            : (d<FD+HIDD) ? o1[(size_t)i*HIDD + d-FD]
            : o2[(size_t)i*HIDD + d-FD-HIDD];
    const float* s = sw + (size_t)d*10;
    #pragma unroll
    for(int o=0;o<10;o++) acc[o] += v*s[o];
  }
  #pragma unroll
  for(int o=0;o<10;o++){
    float t = acc[o];
    for(int off=32;off;off>>=1) t += __shfl_down(t,off);
    if(l==0) out[(size_t)i*10 + o] = t + clsb[o];
  }
}

extern "C" void kernel_launch(void* const* d_in, const int* in_sizes, int n_in,
                              void* d_out, int out_size, void* d_ws, size_t ws_size,
                              hipStream_t stream) {
  const float* x      = (const float*)d_in[0];
  const int*   ei     = (const int*)d_in[1];
  const float* eattr  = (const float*)d_in[2];
  const float* gn1_w  = (const float*)d_in[3];
  const float* gn1_b  = (const float*)d_in[4];
  const float* gn1_ms = (const float*)d_in[5];
  const float* gn2_w  = (const float*)d_in[6];
  const float* gn2_b  = (const float*)d_in[7];
  const float* gn2_ms = (const float*)d_in[8];
  const float* hg1_W  = (const float*)d_in[9];
  const float* hg1_att= (const float*)d_in[10];
  const float* hg1_b  = (const float*)d_in[11];
  const float* hg2_W  = (const float*)d_in[12];
  const float* hg2_att= (const float*)d_in[13];
  const float* hg2_b  = (const float*)d_in[14];
  const float* fc1_W  = (const float*)d_in[15];
  const float* fc1_b  = (const float*)d_in[16];
  const float* fc2_W  = (const float*)d_in[17];
  const float* fc2_b  = (const float*)d_in[18];
  const float* attn_W1= (const float*)d_in[19];
  const float* attn_b1= (const float*)d_in[20];
  const float* attn_W2= (const float*)d_in[21];
  const float* attn_b2= (const float*)d_in[22];
  const float* cls_W  = (const float*)d_in[23];
  const float* cls_b  = (const float*)d_in[24];
  const float* center = (const float*)d_in[25];
  float* out = (float*)d_out;

  const int* row = ei;
  const int* col = ei + NNZE;

  char* w = (char*)d_ws;
  size_t off = 0;
  auto alloc = [&](size_t bytes)->void*{
    off = (off + 255) & ~(size_t)255;
    void* p = w + off;
    off += bytes;
    return p;
  };
  float* xt    = (float*)alloc((size_t)NN*FD*4);
  float* ef    = (float*)alloc((size_t)NN*FD*4);     // later aliased as catT (bf16, same byte size)
  float* h     = (float*)alloc((size_t)NN*FD*4);
  float* out1  = (float*)alloc((size_t)NN*HIDD*4);
  float* out2  = (float*)alloc((size_t)NN*HIDD*4);
  short* inb   = (short*)alloc((size_t)NN*FD*2);
  short* wb    = (short*)alloc((size_t)FD*FD*2);
  int* cnt_col = (int*)alloc(NN*4);
  int* cnt_row = (int*)alloc(NN*4);
  int* col_off = (int*)alloc((NN+1)*4);
  int* row_off = (int*)alloc((NN+1)*4);
  int* col_cur = (int*)alloc(NN*4);
  int* row_cur = (int*)alloc(NN*4);
  int* ceids   = (int*)alloc(NNZE*4);
  int* reids   = (int*)alloc(NNZE*4);
  float* Bn    = (float*)alloc(NN*4);
  float* Dn    = (float*)alloc(NN*4);
  float* a_x   = (float*)alloc(NN*4);
  float* a_e   = (float*)alloc(NN*4);
  float* araw  = (float*)alloc(NNZE*4);
  float* eexp  = (float*)alloc(NNZE*4);
  float* asm_  = (float*)alloc(NNZE*4);
  unsigned* segmax = (unsigned*)alloc(NN*4);
  float* esum  = (float*)alloc(NN*4);
  float* gsum  = (float*)alloc(FD*4);
  float* gssq  = (float*)alloc(FD*4);
  float* gnA   = (float*)alloc(FD*4);
  float* gnB   = (float*)alloc(FD*4);
  float* wx    = (float*)alloc(FD*4);
  float* we    = (float*)alloc(FD*4);
  float* aconst= (float*)alloc(256);
  float* score_pre = (float*)alloc(DCATD*4);
  float* sw    = (float*)alloc(DCATD*10*4);
  short* catT  = (short*)ef;   // alias: ef dead by the time catT is built
  (void)ws_size; (void)n_in; (void)in_sizes; (void)out_size;

  // ---- CSR build ----
  hipMemsetAsync(cnt_col, 0, NN*4, stream);
  hipMemsetAsync(cnt_row, 0, NN*4, stream);
  k_hist<<<NNZE/256, 256, 0, stream>>>(row, col, cnt_row, cnt_col);
  k_scan8192<<<1, 1024, 0, stream>>>(cnt_col, col_off, col_cur);
  k_scan8192<<<1, 1024, 0, stream>>>(cnt_row, row_off, row_cur);
  k_scatter<<<NNZE/256, 256, 0, stream>>>(row, col, col_cur, row_cur, ceids, reids);
  k_deg<<<NN/256, 256, 0, stream>>>(cnt_col, cnt_row, Bn, Dn);

  for(int layer=0; layer<2; layer++){
    const float* src_feat = (layer==0) ? x : h;         // input of this layer (f32)
    const float* gW   = (layer==0) ? gn1_w  : gn2_w;
    const float* gB   = (layer==0) ? gn1_b  : gn2_b;
    const float* gMS  = (layer==0) ? gn1_ms : gn2_ms;
    const float* hgW  = (layer==0) ? hg1_W  : hg2_W;
    const float* hgAtt= (layer==0) ? hg1_att: hg2_att;
    const float* hgB  = (layer==0) ? hg1_b  : hg2_b;
    const float* fcW  = (layer==0) ? fc1_W  : fc2_W;
    const float* fcB  = (layer==0) ? fc1_b  : fc2_b;
    float* fout       = (layer==0) ? out1   : out2;

    // GraphNorm affine coeffs
    hipMemsetAsync(gsum, 0, FD*4, stream);
    hipMemsetAsync(gssq, 0, FD*4, stream);
    k_colstats<<<dim3(3,32), 256, 0, stream>>>(src_feat, gsum, gssq);
    k_gn_fin<<<3, 256, 0, stream>>>(gsum, gssq, gW, gB, gMS, gnA, gnB);

    // a_x / a_e via factored matvecs (exact reassociation, f32)
    hipMemsetAsync(aconst, 0, 4, stream);
    k_watt<<<FD, 256, 0, stream>>>(hgW, hgAtt, gnA, gnB, wx, we, aconst);
    k_matvec<<<NN, 64, 0, stream>>>(src_feat, wx, aconst, a_x);
    k_matvec<<<NN, 64, 0, stream>>>(eattr, we, nullptr, a_e);

    // xt = graphnorm(src) @ hgW^T   (bf16 MFMA)
    k_affcast<<<(NN*FD)/256, 256, 0, stream>>>(src_feat, gnA, gnB, inb);
    k_cast_bf16<<<(FD*FD)/256, 256, 0, stream>>>(hgW, wb, FD*FD);
    gemm_nt<<<dim3(FD/64, NN/256), 256, 0, stream>>>(inb, wb, xt, NN, FD, FD, nullptr, 1.f);

    // segment softmax over hyperedges (col)
    hipMemsetAsync(segmax, 0, NN*4, stream);
    hipMemsetAsync(esum, 0, NN*4, stream);
    k_alpha1<<<NNZE/256, 256, 0, stream>>>(row, col, a_x, a_e, araw, segmax);
    k_alpha2<<<NNZE/256, 256, 0, stream>>>(col, araw, segmax, eexp, esum);
    k_alpha3<<<NNZE/256, 256, 0, stream>>>(col, eexp, esum, asm_);

    // node->hyperedge, hyperedge->node
    k_seg_gather<<<NN, 256, 0, stream>>>(xt, col_off, ceids, row, asm_, Bn, nullptr, 1.f, ef);
    k_seg_gather<<<NN, 256, 0, stream>>>(ef, row_off, reids, col, asm_, Dn, hgB, 0.01f, h);

    // fc: fout = lrelu(h @ fcW^T + fcB, 0.01)
    k_cast_bf16<<<(NN*FD)/256, 256, 0, stream>>>(h, inb, NN*FD);
    k_cast_bf16<<<(HIDD*FD)/256, 256, 0, stream>>>(fcW, wb, HIDD*FD);
    gemm_nt<<<dim3(HIDD/64, NN/256), 256, 0, stream>>>(inb, wb, fout, NN, HIDD, FD, fcB, 0.01f);
  }

  // ---- attention over cat = [x, out1, out2] ----
  k_build_catT<<<dim3(NN/32, DCATD/32), dim3(32,8), 0, stream>>>(x, out1, out2, catT);
  hipMemsetAsync(score_pre, 0, DCATD*4, stream);
  attn_gemm<<<dim3(DCATD/256, NN/64), 256, 0, stream>>>(catT, attn_W1, attn_b1, attn_W2, score_pre);
  k_score<<<DCATD/256, 256, 0, stream>>>(score_pre, attn_b2, center, cls_W, sw);
  k_final<<<NN, 64, 0, stream>>>(x, out1, out2, sw, cls_b, out);
}

// Round 2
// 2063.198 us; speedup vs baseline: 1.0118x; 1.0118x over previous
//
#include <hip/hip_runtime.h>
#include <cstddef>

#define NN 8192
#define FD 768
#define HIDD 384
#define NNZE 131072
#define DCATD 1536

typedef short bf16x8 __attribute__((ext_vector_type(8)));
typedef float f32x4 __attribute__((ext_vector_type(4)));

__device__ __forceinline__ short f2bf(float f){
  unsigned u = __float_as_uint(f);
  unsigned r = u + 0x7FFFu + ((u>>16)&1u);   // RNE
  return (short)(r>>16);
}
__device__ __forceinline__ unsigned fmapu(float f){
  unsigned u = __float_as_uint(f);
  return (u & 0x80000000u) ? ~u : (u | 0x80000000u);
}
__device__ __forceinline__ float funmapu(unsigned m){
  unsigned u = (m & 0x80000000u) ? (m & 0x7FFFFFFFu) : ~m;
  return __uint_as_float(u);
}

// ---------------- CSR build ----------------
__global__ void k_hist(const int* __restrict__ row, const int* __restrict__ col,
                       int* __restrict__ cr, int* __restrict__ cc){
  int e = blockIdx.x*256 + threadIdx.x;
  if(e >= NNZE) return;
  atomicAdd(&cc[col[e]], 1);
  atomicAdd(&cr[row[e]], 1);
}

__global__ __launch_bounds__(1024) void k_scan8192(const int* __restrict__ cnt,
                                                   int* __restrict__ offs, int* __restrict__ cur){
  __shared__ int part[1024];
  int t = threadIdx.x;
  int v[8]; int s = 0;
  #pragma unroll
  for(int j=0;j<8;j++){ v[j]=cnt[t*8+j]; s+=v[j]; }
  part[t]=s; __syncthreads();
  for(int d=1; d<1024; d<<=1){
    int mine = part[t];
    int add = (t>=d)? part[t-d] : 0;
    __syncthreads();
    part[t] = mine + add;
    __syncthreads();
  }
  int excl = part[t]-s;
  #pragma unroll
  for(int j=0;j<8;j++){ offs[t*8+j]=excl; cur[t*8+j]=excl; excl+=v[j]; }
  if(t==1023) offs[8192]=excl;
}

__global__ void k_scatter(const int* __restrict__ row, const int* __restrict__ col,
                          int* __restrict__ ccur, int* __restrict__ rcur,
                          int* __restrict__ ceids, int* __restrict__ reids){
  int e = blockIdx.x*256 + threadIdx.x;
  if(e >= NNZE) return;
  int p = atomicAdd(&ccur[col[e]],1); ceids[p]=e;
  int q = atomicAdd(&rcur[row[e]],1); reids[q]=e;
}

__global__ void k_deg(const int* __restrict__ cc, const int* __restrict__ cr,
                      float* __restrict__ Bn, float* __restrict__ Dn){
  int i = blockIdx.x*256 + threadIdx.x;
  if(i>=NN) return;
  int c=cc[i]; Bn[i] = c>0 ? 1.f/(float)c : 0.f;
  int r=cr[i]; Dn[i] = r>0 ? 1.f/(float)r : 0.f;
}

// ---------------- GraphNorm ----------------
__global__ __launch_bounds__(256) void k_colstats(const float* __restrict__ src,
                                                  float* __restrict__ gs, float* __restrict__ gss){
  int col = blockIdx.x*256 + threadIdx.x;     // 0..767
  int r0 = blockIdx.y*256;
  float s1=0.f, s2=0.f;
  for(int r=0;r<256;r++){
    float v = src[(size_t)(r0+r)*FD + col];
    s1+=v; s2+=v*v;
  }
  atomicAdd(&gs[col], s1);
  atomicAdd(&gss[col], s2);
}

__global__ void k_gn_fin(const float* __restrict__ gs, const float* __restrict__ gss,
                         const float* __restrict__ w_, const float* __restrict__ b_,
                         const float* __restrict__ ms_, float* __restrict__ A, float* __restrict__ B){
  int c = blockIdx.x*256 + threadIdx.x;
  if(c>=FD) return;
  float mean = gs[c]*(1.f/(float)NN);
  float ex2  = gss[c]*(1.f/(float)NN);
  float ctr  = ms_[c]*mean;
  float var  = ex2 - 2.f*ctr*mean + ctr*ctr;
  float a    = w_[c] / sqrtf(var + 1e-5f);
  A[c]=a; B[c]=b_[c] - a*ctr;
}

// ---------------- casts ----------------
__global__ void k_cast_bf16(const float* __restrict__ s, short* __restrict__ d, int n){
  int i = blockIdx.x*256+threadIdx.x;
  if(i<n) d[i]=f2bf(s[i]);
}
__global__ void k_affcast(const float* __restrict__ s, const float* __restrict__ A,
                          const float* __restrict__ B, short* __restrict__ d){
  int i = blockIdx.x*256+threadIdx.x;   // NN*FD total
  if(i>=NN*FD) return;
  int c = i - (i/FD)*FD;
  d[i] = f2bf(A[c]*s[i] + B[c]);
}

// vectorized f32 -> bf16 (8 elems/thread), n must be multiple of 2048
__global__ __launch_bounds__(256) void k_cvt8(const float* __restrict__ s, short* __restrict__ d){
  size_t base = ((size_t)blockIdx.x*256 + threadIdx.x)*8;
  float4 f0 = *(const float4*)(s+base);
  float4 f1 = *(const float4*)(s+base+4);
  bf16x8 t;
  t[0]=f2bf(f0.x); t[1]=f2bf(f0.y); t[2]=f2bf(f0.z); t[3]=f2bf(f0.w);
  t[4]=f2bf(f1.x); t[5]=f2bf(f1.y); t[6]=f2bf(f1.z); t[7]=f2bf(f1.w);
  *(bf16x8*)(d+base) = t;
}

// ---------------- bf16 NT GEMM: C[M,N] = A[M,K] @ B[N,K]^T (+bias, lrelu) ----------------
__global__ __launch_bounds__(256) void gemm_nt(const short* __restrict__ A, const short* __restrict__ B,
    float* __restrict__ C, int M, int N, int K,
    const float* __restrict__ bias, float slope){
  int lane = threadIdx.x & 63;
  int wv   = threadIdx.x >> 6;
  int m0 = (blockIdx.y*4 + wv)*64;
  int n0 = blockIdx.x*64;
  int li = lane & 15, q = lane >> 4;
  const short* Ab = A + (size_t)(m0+li)*K + q*8;
  const short* Bb = B + (size_t)(n0+li)*K + q*8;
  f32x4 acc[4][4];
  #pragma unroll
  for(int i=0;i<4;i++)
    #pragma unroll
    for(int j=0;j<4;j++) acc[i][j] = (f32x4){0.f,0.f,0.f,0.f};
  for(int k0=0;k0<K;k0+=32){
    bf16x8 a[4], b[4];
    #pragma unroll
    for(int i=0;i<4;i++) a[i] = *(const bf16x8*)(Ab + (size_t)i*16*K + k0);
    #pragma unroll
    for(int j=0;j<4;j++) b[j] = *(const bf16x8*)(Bb + (size_t)j*16*K + k0);
    #pragma unroll
    for(int i=0;i<4;i++)
      #pragma unroll
      for(int j=0;j<4;j++)
        acc[i][j] = __builtin_amdgcn_mfma_f32_16x16x32_bf16(a[i], b[j], acc[i][j], 0, 0, 0);
  }
  #pragma unroll
  for(int i=0;i<4;i++){
    int gm = m0 + i*16 + q*4;
    #pragma unroll
    for(int j=0;j<4;j++){
      int gn = n0 + j*16 + li;
      float bv = bias ? bias[gn] : 0.f;
      #pragma unroll
      for(int r=0;r<4;r++){
        float vv = acc[i][j][r] + bv;
        vv = (vv>=0.f) ? vv : vv*slope;
        C[(size_t)(gm+r)*N + gn] = vv;
      }
    }
  }
}

// ---------------- watt ----------------
__global__ __launch_bounds__(256) void k_watt(const float* __restrict__ W, const float* __restrict__ att,
    const float* __restrict__ gnA, const float* __restrict__ gnB,
    float* __restrict__ wx, float* __restrict__ we, float* __restrict__ aconst){
  int c = blockIdx.x; int t = threadIdx.x;
  float sA=0.f, sB=0.f;
  for(int f=t; f<FD; f+=256){
    float w = W[(size_t)f*FD + c];
    sA += w*att[f];
    sB += w*att[FD+f];
  }
  __shared__ float shA[256], shB[256];
  shA[t]=sA; shB[t]=sB; __syncthreads();
  for(int s=128;s>0;s>>=1){ if(t<s){ shA[t]+=shA[t+s]; shB[t]+=shB[t+s]; } __syncthreads(); }
  if(t==0){ float a=shA[0]; wx[c]=gnA[c]*a; we[c]=shB[0]; atomicAdd(aconst, gnB[c]*a); }
}

// a[i] = sum_c src[i,c]*wv[c] (+ cst)
__global__ __launch_bounds__(64) void k_matvec(const float* __restrict__ src, const float* __restrict__ wv,
    const float* __restrict__ cst, float* __restrict__ out){
  int i = blockIdx.x, l = threadIdx.x;
  float s=0.f;
  for(int c=l;c<FD;c+=64) s += src[(size_t)i*FD+c]*wv[c];
  for(int o=32;o;o>>=1) s += __shfl_down(s,o);
  if(l==0) out[i] = s + (cst ? cst[0] : 0.f);
}

// ---------------- alpha / segment softmax ----------------
__global__ void k_alpha1(const int* __restrict__ row, const int* __restrict__ col,
                         const float* __restrict__ ax, const float* __restrict__ ae,
                         float* __restrict__ araw, unsigned* __restrict__ segmax){
  int e = blockIdx.x*256 + threadIdx.x;
  if(e>=NNZE) return;
  float a = ax[row[e]] + ae[col[e]];
  a = (a>=0.f) ? a : 0.2f*a;
  araw[e]=a;
  atomicMax(&segmax[col[e]], fmapu(a));
}
__global__ void k_alpha2(const int* __restrict__ col, const float* __restrict__ araw,
                         const unsigned* __restrict__ segmax,
                         float* __restrict__ eexp, float* __restrict__ esum){
  int e = blockIdx.x*256 + threadIdx.x;
  if(e>=NNZE) return;
  float m = funmapu(segmax[col[e]]);
  float x = expf(araw[e]-m);
  eexp[e]=x;
  atomicAdd(&esum[col[e]], x);
}
__global__ void k_alpha3(const int* __restrict__ col, const float* __restrict__ eexp,
                         const float* __restrict__ esum, float* __restrict__ asm_){
  int e = blockIdx.x*256 + threadIdx.x;
  if(e>=NNZE) return;
  asm_[e] = eexp[e] / (esum[col[e]] + 1e-16f);
}

// ---------------- segment gather-sum over 768-wide rows ----------------
__global__ __launch_bounds__(256) void k_seg_gather(const float* __restrict__ src,
    const int* __restrict__ offs, const int* __restrict__ eids,
    const int* __restrict__ gidx, const float* __restrict__ alpha_sm,
    const float* __restrict__ segscale, const float* __restrict__ bias, float slope,
    float* __restrict__ dst){
  int c = blockIdx.x, t = threadIdx.x;
  int beg = offs[c], end = offs[c+1];
  float scale = segscale[c];
  __shared__ float wsh[256]; __shared__ int rsh[256];
  float a0=0.f,a1=0.f,a2=0.f;
  for(int base=beg; base<end; base+=256){
    int idx = base+t;
    if(idx<end){ int e=eids[idx]; wsh[t]=alpha_sm[e]; rsh[t]=gidx[e]; }
    __syncthreads();
    int cnt = min(256, end-base);
    for(int j=0;j<cnt;j++){
      float wj = wsh[j];
      const float* r = src + (size_t)rsh[j]*FD;
      a0 += wj*r[t]; a1 += wj*r[t+256]; a2 += wj*r[t+512];
    }
    __syncthreads();
  }
  a0*=scale; a1*=scale; a2*=scale;
  if(bias){
    a0+=bias[t]; a1+=bias[t+256]; a2+=bias[t+512];
    a0=(a0>=0.f)?a0:slope*a0; a1=(a1>=0.f)?a1:slope*a1; a2=(a2>=0.f)?a2:slope*a2;
  }
  dst[(size_t)c*FD+t]=a0; dst[(size_t)c*FD+t+256]=a1; dst[(size_t)c*FD+t+512]=a2;
}

// ---------------- catT build ----------------
__global__ __launch_bounds__(256) void k_build_catT(const float* __restrict__ x,
    const float* __restrict__ o1, const float* __restrict__ o2, short* __restrict__ catT){
  __shared__ float tile[32][33];
  int i0 = blockIdx.x*32, d0 = blockIdx.y*32;
  int tx = threadIdx.x, ty = threadIdx.y;   // 32 x 8
  const float* src; int dof, ld;
  if(d0 < FD){ src=x; dof=d0; ld=FD; }
  else if(d0 < FD+HIDD){ src=o1; dof=d0-FD; ld=HIDD; }
  else { src=o2; dof=d0-FD-HIDD; ld=HIDD; }
  for(int yy=ty; yy<32; yy+=8)
    tile[yy][tx] = src[(size_t)(i0+yy)*ld + dof + tx];
  __syncthreads();
  for(int yy=ty; yy<32; yy+=8)
    catT[(size_t)(d0+yy)*NN + i0 + tx] = f2bf(tile[tx][yy]);
}

// ---------------- attention mega-GEMM (bf16 W1, XCD swizzle, 1-deep prefetch) ----------------
// grid: 768 blocks 1-D. Swizzle: blocks with same n0 land on same XCD (id%8 class)
// so the 6 m-replicas share W1b rows through that XCD's L2.
__global__ __launch_bounds__(256) void attn_gemm_bf(const short* __restrict__ catT,
    const short* __restrict__ W1b, const float* __restrict__ b1, const float* __restrict__ W2,
    float* __restrict__ score_pre){
  const int K = NN;
  int b = blockIdx.x;               // 0..767
  int m_idx = (b>>3) % 6;           // 0..5
  int n_idx = (b/48)*8 + (b&7);     // 0..127
  int lane = threadIdx.x & 63;
  int wv   = threadIdx.x >> 6;
  int m0 = m_idx*256 + wv*64;
  int n0 = n_idx*64;
  int li = lane & 15, q = lane >> 4;
  const short* Ab = catT + (size_t)(m0+li)*K + q*8;
  const short* Bb = W1b + (size_t)(n0+li)*K + q*8;
  f32x4 acc[4][4];
  #pragma unroll
  for(int i=0;i<4;i++)
    #pragma unroll
    for(int j=0;j<4;j++) acc[i][j] = (f32x4){0.f,0.f,0.f,0.f};
  bf16x8 a[4], bfr[4], an[4], bn[4];
  #pragma unroll
  for(int i=0;i<4;i++) a[i] = *(const bf16x8*)(Ab + (size_t)i*16*K);
  #pragma unroll
  for(int j=0;j<4;j++) bfr[j] = *(const bf16x8*)(Bb + (size_t)j*16*K);
  for(int k0=32;k0<K;k0+=32){
    #pragma unroll
    for(int i=0;i<4;i++) an[i] = *(const bf16x8*)(Ab + (size_t)i*16*K + k0);
    #pragma unroll
    for(int j=0;j<4;j++) bn[j] = *(const bf16x8*)(Bb + (size_t)j*16*K + k0);
    #pragma unroll
    for(int i=0;i<4;i++)
      #pragma unroll
      for(int j=0;j<4;j++)
        acc[i][j] = __builtin_amdgcn_mfma_f32_16x16x32_bf16(a[i], bfr[j], acc[i][j], 0, 0, 0);
    #pragma unroll
    for(int i=0;i<4;i++) a[i]=an[i];
    #pragma unroll
    for(int j=0;j<4;j++) bfr[j]=bn[j];
  }
  #pragma unroll
  for(int i=0;i<4;i++)
    #pragma unroll
    for(int j=0;j<4;j++)
      acc[i][j] = __builtin_amdgcn_mfma_f32_16x16x32_bf16(a[i], bfr[j], acc[i][j], 0, 0, 0);
  float w2v[4], b1v[4];
  #pragma unroll
  for(int j=0;j<4;j++){ int gn=n0+j*16+li; w2v[j]=W2[gn]; b1v[j]=b1[gn]; }
  #pragma unroll
  for(int i=0;i<4;i++){
    #pragma unroll
    for(int r=0;r<4;r++){
      float s=0.f;
      #pragma unroll
      for(int j=0;j<4;j++){
        float v = acc[i][j][r] + b1v[j];
        v = v>0.f ? v : 0.f;
        s += v*w2v[j];
      }
      s += __shfl_xor(s,1); s += __shfl_xor(s,2); s += __shfl_xor(s,4); s += __shfl_xor(s,8);
      if(li==0) atomicAdd(&score_pre[m0 + i*16 + q*4 + r], s);
    }
  }
}

// fallback (on-the-fly f32->bf16 cvt) if ws can't hold W1b
__global__ __launch_bounds__(256) void attn_gemm_f32(const short* __restrict__ catT,
    const float* __restrict__ W1, const float* __restrict__ b1, const float* __restrict__ W2,
    float* __restrict__ score_pre){
  const int K = NN;
  int lane = threadIdx.x & 63;
  int wv   = threadIdx.x >> 6;
  int m0 = (blockIdx.x*4 + wv)*64;
  int n0 = blockIdx.y*64;
  int li = lane & 15, q = lane >> 4;
  const short* Ab = catT + (size_t)(m0+li)*K + q*8;
  const float* Bb = W1 + (size_t)(n0+li)*K + q*8;
  f32x4 acc[4][4];
  #pragma unroll
  for(int i=0;i<4;i++)
    #pragma unroll
    for(int j=0;j<4;j++) acc[i][j] = (f32x4){0.f,0.f,0.f,0.f};
  for(int k0=0;k0<K;k0+=32){
    bf16x8 a[4], b[4];
    #pragma unroll
    for(int i=0;i<4;i++) a[i] = *(const bf16x8*)(Ab + (size_t)i*16*K + k0);
    #pragma unroll
    for(int j=0;j<4;j++){
      const float* p = Bb + (size_t)j*16*K + k0;
      float4 f0 = *(const float4*)p;
      float4 f1 = *(const float4*)(p+4);
      bf16x8 t;
      t[0]=f2bf(f0.x); t[1]=f2bf(f0.y); t[2]=f2bf(f0.z); t[3]=f2bf(f0.w);
      t[4]=f2bf(f1.x); t[5]=f2bf(f1.y); t[6]=f2bf(f1.z); t[7]=f2bf(f1.w);
      b[j]=t;
    }
    #pragma unroll
    for(int i=0;i<4;i++)
      #pragma unroll
      for(int j=0;j<4;j++)
        acc[i][j] = __builtin_amdgcn_mfma_f32_16x16x32_bf16(a[i], b[j], acc[i][j], 0, 0, 0);
  }
  float w2v[4], b1v[4];
  #pragma unroll
  for(int j=0;j<4;j++){ int gn=n0+j*16+li; w2v[j]=W2[gn]; b1v[j]=b1[gn]; }
  #pragma unroll
  for(int i=0;i<4;i++){
    #pragma unroll
    for(int r=0;r<4;r++){
      float s=0.f;
      #pragma unroll
      for(int j=0;j<4;j++){
        float v = acc[i][j][r] + b1v[j];
        v = v>0.f ? v : 0.f;
        s += v*w2v[j];
      }
      s += __shfl_xor(s,1); s += __shfl_xor(s,2); s += __shfl_xor(s,4); s += __shfl_xor(s,8);
      if(li==0) atomicAdd(&score_pre[m0 + i*16 + q*4 + r], s);
    }
  }
}

// ---------------- score finalize ----------------
__global__ void k_score(const float* __restrict__ pre, const float* __restrict__ b2,
                        const float* __restrict__ center, const float* __restrict__ clsW,
                        float* __restrict__ sw){
  int d = blockIdx.x*256 + threadIdx.x;
  if(d>=DCATD) return;
  float sc = pre[d] + b2[0];
  sc = 1.f/(1.f+expf(-sc));
  sc -= center[d];
  #pragma unroll
  for(int o=0;o<10;o++) sw[d*10+o] = sc * clsW[(size_t)o*DCATD + d];
}

// ---------------- final ----------------
__global__ __launch_bounds__(64) void k_final(const float* __restrict__ x, const float* __restrict__ o1,
    const float* __restrict__ o2, const float* __restrict__ sw, const float* __restrict__ clsb,
    float* __restrict__ out){
  int i = blockIdx.x, l = threadIdx.x;
  float acc[10];
  #pragma unroll
  for(int o=0;o<10;o++) acc[o]=0.f;
  for(int d=l; d<DCATD; d+=64){
    float v = (d<FD) ? x[(size_t)i*FD + d]
            : (d<FD+HIDD) ? o1[(size_t)i*HIDD + d-FD]
            : o2[(size_t)i*HIDD + d-FD-HIDD];
    const float* s = sw + (size_t)d*10;
    #pragma unroll
    for(int o=0;o<10;o++) acc[o] += v*s[o];
  }
  #pragma unroll
  for(int o=0;o<10;o++){
    float t = acc[o];
    for(int off=32;off;off>>=1) t += __shfl_down(t,off);
    if(l==0) out[(size_t)i*10 + o] = t + clsb[o];
  }
}

extern "C" void kernel_launch(void* const* d_in, const int* in_sizes, int n_in,
                              void* d_out, int out_size, void* d_ws, size_t ws_size,
                              hipStream_t stream) {
  const float* x      = (const float*)d_in[0];
  const int*   ei     = (const int*)d_in[1];
  const float* eattr  = (const float*)d_in[2];
  const float* gn1_w  = (const float*)d_in[3];
  const float* gn1_b  = (const float*)d_in[4];
  const float* gn1_ms = (const float*)d_in[5];
  const float* gn2_w  = (const float*)d_in[6];
  const float* gn2_b  = (const float*)d_in[7];
  const float* gn2_ms = (const float*)d_in[8];
  const float* hg1_W  = (const float*)d_in[9];
  const float* hg1_att= (const float*)d_in[10];
  const float* hg1_b  = (const float*)d_in[11];
  const float* hg2_W  = (const float*)d_in[12];
  const float* hg2_att= (const float*)d_in[13];
  const float* hg2_b  = (const float*)d_in[14];
  const float* fc1_W  = (const float*)d_in[15];
  const float* fc1_b  = (const float*)d_in[16];
  const float* fc2_W  = (const float*)d_in[17];
  const float* fc2_b  = (const float*)d_in[18];
  const float* attn_W1= (const float*)d_in[19];
  const float* attn_b1= (const float*)d_in[20];
  const float* attn_W2= (const float*)d_in[21];
  const float* attn_b2= (const float*)d_in[22];
  const float* cls_W  = (const float*)d_in[23];
  const float* cls_b  = (const float*)d_in[24];
  const float* center = (const float*)d_in[25];
  float* out = (float*)d_out;

  const int* row = ei;
  const int* col = ei + NNZE;

  char* w = (char*)d_ws;
  size_t off = 0;
  auto alloc = [&](size_t bytes)->void*{
    off = (off + 255) & ~(size_t)255;
    void* p = w + off;
    off += bytes;
    return p;
  };
  float* xt    = (float*)alloc((size_t)NN*FD*4);
  float* ef    = (float*)alloc((size_t)NN*FD*4);     // later aliased as catT (bf16)
  float* h     = (float*)alloc((size_t)NN*FD*4);
  float* out1  = (float*)alloc((size_t)NN*HIDD*4);
  float* out2  = (float*)alloc((size_t)NN*HIDD*4);
  short* inb   = (short*)alloc((size_t)NN*FD*2);
  short* wb    = (short*)alloc((size_t)FD*FD*2);
  int* cnt_col = (int*)alloc(NN*4);
  int* cnt_row = (int*)alloc(NN*4);
  int* col_off = (int*)alloc((NN+1)*4);
  int* row_off = (int*)alloc((NN+1)*4);
  int* col_cur = (int*)alloc(NN*4);
  int* row_cur = (int*)alloc(NN*4);
  int* ceids   = (int*)alloc(NNZE*4);
  int* reids   = (int*)alloc(NNZE*4);
  float* Bn    = (float*)alloc(NN*4);
  float* Dn    = (float*)alloc(NN*4);
  float* a_x   = (float*)alloc(NN*4);
  float* a_e   = (float*)alloc(NN*4);
  float* araw  = (float*)alloc(NNZE*4);
  float* eexp  = (float*)alloc(NNZE*4);
  float* asm_  = (float*)alloc(NNZE*4);
  unsigned* segmax = (unsigned*)alloc(NN*4);
  float* esum  = (float*)alloc(NN*4);
  float* gsum  = (float*)alloc(FD*4);
  float* gssq  = (float*)alloc(FD*4);
  float* gnA   = (float*)alloc(FD*4);
  float* gnB   = (float*)alloc(FD*4);
  float* wx    = (float*)alloc(FD*4);
  float* we    = (float*)alloc(FD*4);
  float* aconst= (float*)alloc(256);
  float* score_pre = (float*)alloc(DCATD*4);
  float* sw    = (float*)alloc(DCATD*10*4);
  short* catT  = (short*)ef;   // alias: ef dead by the time catT is built
  // W1 bf16 copy — only if workspace has room (134 MB)
  size_t off_before_w1b = off;
  short* W1b   = (short*)alloc((size_t)NN*NN*2);
  bool use_w1b = (off <= ws_size);
  if(!use_w1b) off = off_before_w1b;
  (void)n_in; (void)in_sizes; (void)out_size;

  // ---- CSR build ----
  hipMemsetAsync(cnt_col, 0, NN*4, stream);
  hipMemsetAsync(cnt_row, 0, NN*4, stream);
  k_hist<<<NNZE/256, 256, 0, stream>>>(row, col, cnt_row, cnt_col);
  k_scan8192<<<1, 1024, 0, stream>>>(cnt_col, col_off, col_cur);
  k_scan8192<<<1, 1024, 0, stream>>>(cnt_row, row_off, row_cur);
  k_scatter<<<NNZE/256, 256, 0, stream>>>(row, col, col_cur, row_cur, ceids, reids);
  k_deg<<<NN/256, 256, 0, stream>>>(cnt_col, cnt_row, Bn, Dn);

  // convert attn_W1 to bf16 early (overlaps nothing, but primes before attn)
  if(use_w1b)
    k_cvt8<<<(NN*(size_t)NN)/8/256, 256, 0, stream>>>(attn_W1, W1b);

  for(int layer=0; layer<2; layer++){
    const float* src_feat = (layer==0) ? x : h;
    const float* gW   = (layer==0) ? gn1_w  : gn2_w;
    const float* gB   = (layer==0) ? gn1_b  : gn2_b;
    const float* gMS  = (layer==0) ? gn1_ms : gn2_ms;
    const float* hgW  = (layer==0) ? hg1_W  : hg2_W;
    const float* hgAtt= (layer==0) ? hg1_att: hg2_att;
    const float* hgB  = (layer==0) ? hg1_b  : hg2_b;
    const float* fcW  = (layer==0) ? fc1_W  : fc2_W;
    const float* fcB  = (layer==0) ? fc1_b  : fc2_b;
    float* fout       = (layer==0) ? out1   : out2;

    hipMemsetAsync(gsum, 0, FD*4, stream);
    hipMemsetAsync(gssq, 0, FD*4, stream);
    k_colstats<<<dim3(3,32), 256, 0, stream>>>(src_feat, gsum, gssq);
    k_gn_fin<<<3, 256, 0, stream>>>(gsum, gssq, gW, gB, gMS, gnA, gnB);

    hipMemsetAsync(aconst, 0, 4, stream);
    k_watt<<<FD, 256, 0, stream>>>(hgW, hgAtt, gnA, gnB, wx, we, aconst);
    k_matvec<<<NN, 64, 0, stream>>>(src_feat, wx, aconst, a_x);
    k_matvec<<<NN, 64, 0, stream>>>(eattr, we, nullptr, a_e);

    k_affcast<<<(NN*FD)/256, 256, 0, stream>>>(src_feat, gnA, gnB, inb);
    k_cast_bf16<<<(FD*FD)/256, 256, 0, stream>>>(hgW, wb, FD*FD);
    gemm_nt<<<dim3(FD/64, NN/256), 256, 0, stream>>>(inb, wb, xt, NN, FD, FD, nullptr, 1.f);

    hipMemsetAsync(segmax, 0, NN*4, stream);
    hipMemsetAsync(esum, 0, NN*4, stream);
    k_alpha1<<<NNZE/256, 256, 0, stream>>>(row, col, a_x, a_e, araw, segmax);
    k_alpha2<<<NNZE/256, 256, 0, stream>>>(col, araw, segmax, eexp, esum);
    k_alpha3<<<NNZE/256, 256, 0, stream>>>(col, eexp, esum, asm_);

    k_seg_gather<<<NN, 256, 0, stream>>>(xt, col_off, ceids, row, asm_, Bn, nullptr, 1.f, ef);
    k_seg_gather<<<NN, 256, 0, stream>>>(ef, row_off, reids, col, asm_, Dn, hgB, 0.01f, h);

    k_cast_bf16<<<(NN*FD)/256, 256, 0, stream>>>(h, inb, NN*FD);
    k_cast_bf16<<<(HIDD*FD)/256, 256, 0, stream>>>(fcW, wb, HIDD*FD);
    gemm_nt<<<dim3(HIDD/64, NN/256), 256, 0, stream>>>(inb, wb, fout, NN, HIDD, FD, fcB, 0.01f);
  }

  // ---- attention over cat = [x, out1, out2] ----
  k_build_catT<<<dim3(NN/32, DCATD/32), dim3(32,8), 0, stream>>>(x, out1, out2, catT);
  hipMemsetAsync(score_pre, 0, DCATD*4, stream);
  if(use_w1b)
    attn_gemm_bf<<<768, 256, 0, stream>>>(catT, W1b, attn_b1, attn_W2, score_pre);
  else
    attn_gemm_f32<<<dim3(DCATD/256, NN/64), 256, 0, stream>>>(catT, attn_W1, attn_b1, attn_W2, score_pre);
  k_score<<<DCATD/256, 256, 0, stream>>>(score_pre, attn_b2, center, cls_W, sw);
  k_final<<<NN, 64, 0, stream>>>(x, out1, out2, sw, cls_b, out);
}

// Round 3
// 1329.537 us; speedup vs baseline: 1.5701x; 1.5518x over previous
//
#include <hip/hip_runtime.h>
#include <cstddef>

#define NN 8192
#define FD 768
#define HIDD 384
#define NNZE 131072
#define DCATD 1536

typedef short bf16x8 __attribute__((ext_vector_type(8)));
typedef float f32x4 __attribute__((ext_vector_type(4)));

__device__ __forceinline__ short f2bf(float f){
  unsigned u = __float_as_uint(f);
  unsigned r = u + 0x7FFFu + ((u>>16)&1u);   // RNE
  return (short)(r>>16);
}
__device__ __forceinline__ unsigned fmapu(float f){
  unsigned u = __float_as_uint(f);
  return (u & 0x80000000u) ? ~u : (u | 0x80000000u);
}
__device__ __forceinline__ float funmapu(unsigned m){
  unsigned u = (m & 0x80000000u) ? (m & 0x7FFFFFFFu) : ~m;
  return __uint_as_float(u);
}

// async global -> LDS, 16B per lane. lds ptr must be wave-uniform; HW scatters lane*16.
__device__ __forceinline__ void async_copy16(void* lds, const void* g){
  __builtin_amdgcn_global_load_lds((__attribute__((address_space(1))) void*)g,
                                   (__attribute__((address_space(3))) void*)lds, 16, 0, 0);
}

// ---------------- CSR build ----------------
__global__ void k_hist(const int* __restrict__ row, const int* __restrict__ col,
                       int* __restrict__ cr, int* __restrict__ cc){
  int e = blockIdx.x*256 + threadIdx.x;
  if(e >= NNZE) return;
  atomicAdd(&cc[col[e]], 1);
  atomicAdd(&cr[row[e]], 1);
}

__global__ __launch_bounds__(1024) void k_scan8192(const int* __restrict__ cnt,
                                                   int* __restrict__ offs, int* __restrict__ cur){
  __shared__ int part[1024];
  int t = threadIdx.x;
  int v[8]; int s = 0;
  #pragma unroll
  for(int j=0;j<8;j++){ v[j]=cnt[t*8+j]; s+=v[j]; }
  part[t]=s; __syncthreads();
  for(int d=1; d<1024; d<<=1){
    int mine = part[t];
    int add = (t>=d)? part[t-d] : 0;
    __syncthreads();
    part[t] = mine + add;
    __syncthreads();
  }
  int excl = part[t]-s;
  #pragma unroll
  for(int j=0;j<8;j++){ offs[t*8+j]=excl; cur[t*8+j]=excl; excl+=v[j]; }
  if(t==1023) offs[8192]=excl;
}

__global__ void k_scatter(const int* __restrict__ row, const int* __restrict__ col,
                          int* __restrict__ ccur, int* __restrict__ rcur,
                          int* __restrict__ ceids, int* __restrict__ reids){
  int e = blockIdx.x*256 + threadIdx.x;
  if(e >= NNZE) return;
  int p = atomicAdd(&ccur[col[e]],1); ceids[p]=e;
  int q = atomicAdd(&rcur[row[e]],1); reids[q]=e;
}

__global__ void k_deg(const int* __restrict__ cc, const int* __restrict__ cr,
                      float* __restrict__ Bn, float* __restrict__ Dn){
  int i = blockIdx.x*256 + threadIdx.x;
  if(i>=NN) return;
  int c=cc[i]; Bn[i] = c>0 ? 1.f/(float)c : 0.f;
  int r=cr[i]; Dn[i] = r>0 ? 1.f/(float)r : 0.f;
}

// ---------------- GraphNorm ----------------
__global__ __launch_bounds__(256) void k_colstats(const float* __restrict__ src,
                                                  float* __restrict__ gs, float* __restrict__ gss){
  int col = blockIdx.x*256 + threadIdx.x;     // 0..767
  int r0 = blockIdx.y*256;
  float s1=0.f, s2=0.f;
  for(int r=0;r<256;r++){
    float v = src[(size_t)(r0+r)*FD + col];
    s1+=v; s2+=v*v;
  }
  atomicAdd(&gs[col], s1);
  atomicAdd(&gss[col], s2);
}

__global__ void k_gn_fin(const float* __restrict__ gs, const float* __restrict__ gss,
                         const float* __restrict__ w_, const float* __restrict__ b_,
                         const float* __restrict__ ms_, float* __restrict__ A, float* __restrict__ B){
  int c = blockIdx.x*256 + threadIdx.x;
  if(c>=FD) return;
  float mean = gs[c]*(1.f/(float)NN);
  float ex2  = gss[c]*(1.f/(float)NN);
  float ctr  = ms_[c]*mean;
  float var  = ex2 - 2.f*ctr*mean + ctr*ctr;
  float a    = w_[c] / sqrtf(var + 1e-5f);
  A[c]=a; B[c]=b_[c] - a*ctr;
}

// ---------------- casts ----------------
__global__ void k_cast_bf16(const float* __restrict__ s, short* __restrict__ d, int n){
  int i = blockIdx.x*256+threadIdx.x;
  if(i<n) d[i]=f2bf(s[i]);
}
__global__ void k_affcast(const float* __restrict__ s, const float* __restrict__ A,
                          const float* __restrict__ B, short* __restrict__ d){
  int i = blockIdx.x*256+threadIdx.x;   // NN*FD total
  if(i>=NN*FD) return;
  int c = i - (i/FD)*FD;
  d[i] = f2bf(A[c]*s[i] + B[c]);
}

// vectorized f32 -> bf16 (8 elems/thread), n must be multiple of 2048
__global__ __launch_bounds__(256) void k_cvt8(const float* __restrict__ s, short* __restrict__ d){
  size_t base = ((size_t)blockIdx.x*256 + threadIdx.x)*8;
  float4 f0 = *(const float4*)(s+base);
  float4 f1 = *(const float4*)(s+base+4);
  bf16x8 t;
  t[0]=f2bf(f0.x); t[1]=f2bf(f0.y); t[2]=f2bf(f0.z); t[3]=f2bf(f0.w);
  t[4]=f2bf(f1.x); t[5]=f2bf(f1.y); t[6]=f2bf(f1.z); t[7]=f2bf(f1.w);
  *(bf16x8*)(d+base) = t;
}

// ---------------- m97-style LDS-staged bf16 NT GEMM ----------------
// C[M,N] = A[M,K] @ B[N,K]^T, 128x128 tile, BK=32, global_load_lds width 16.
// M,N multiples of 128; K multiple of 32.
__global__ __launch_bounds__(256) void gemm_lds(const short* __restrict__ A, const short* __restrict__ B,
    float* __restrict__ C, int M, int N, int K,
    const float* __restrict__ bias, float slope){
  __shared__ __align__(16) short As[128*32];
  __shared__ __align__(16) short Bs[128*32];
  int t = threadIdx.x;
  int w = t>>6, l = t&63;
  int m0 = blockIdx.y*128, n0 = blockIdx.x*128;
  int wm = w>>1, wn = w&1;
  int li = l&15, q = l>>4;
  // staging: per issue, wave w covers rows issue*64 + w*16 + (l>>2), k byte-offset (l&3)*16
  const short* Ag = A + (size_t)(m0 + w*16 + (l>>2))*K + (l&3)*8;
  const short* Bg = B + (size_t)(n0 + w*16 + (l>>2))*K + (l&3)*8;
  short* Asl = &As[(w*16)*32];
  short* Bsl = &Bs[(w*16)*32];
  f32x4 acc[4][4];
  #pragma unroll
  for(int i=0;i<4;i++)
    #pragma unroll
    for(int j=0;j<4;j++) acc[i][j] = (f32x4){0.f,0.f,0.f,0.f};
  for(int k0=0;k0<K;k0+=32){
    async_copy16(Asl,          Ag + k0);
    async_copy16(Asl + 64*32,  Ag + (size_t)64*K + k0);
    async_copy16(Bsl,          Bg + k0);
    async_copy16(Bsl + 64*32,  Bg + (size_t)64*K + k0);
    __syncthreads();
    bf16x8 a[4], b[4];
    #pragma unroll
    for(int i=0;i<4;i++) a[i] = *(const bf16x8*)&As[(wm*64 + i*16 + li)*32 + q*8];
    #pragma unroll
    for(int j=0;j<4;j++) b[j] = *(const bf16x8*)&Bs[(wn*64 + j*16 + li)*32 + q*8];
    #pragma unroll
    for(int i=0;i<4;i++)
      #pragma unroll
      for(int j=0;j<4;j++)
        acc[i][j] = __builtin_amdgcn_mfma_f32_16x16x32_bf16(a[i], b[j], acc[i][j], 0, 0, 0);
    __syncthreads();
  }
  #pragma unroll
  for(int i=0;i<4;i++){
    int gm = m0 + wm*64 + i*16 + q*4;
    #pragma unroll
    for(int j=0;j<4;j++){
      int gn = n0 + wn*64 + j*16 + li;
      float bv = bias ? bias[gn] : 0.f;
      #pragma unroll
      for(int r=0;r<4;r++){
        float vv = acc[i][j][r] + bv;
        vv = (vv>=0.f) ? vv : vv*slope;
        C[(size_t)(gm+r)*N + gn] = vv;
      }
    }
  }
}

// ---------------- watt ----------------
__global__ __launch_bounds__(256) void k_watt(const float* __restrict__ W, const float* __restrict__ att,
    const float* __restrict__ gnA, const float* __restrict__ gnB,
    float* __restrict__ wx, float* __restrict__ we, float* __restrict__ aconst){
  int c = blockIdx.x; int t = threadIdx.x;
  float sA=0.f, sB=0.f;
  for(int f=t; f<FD; f+=256){
    float w = W[(size_t)f*FD + c];
    sA += w*att[f];
    sB += w*att[FD+f];
  }
  __shared__ float shA[256], shB[256];
  shA[t]=sA; shB[t]=sB; __syncthreads();
  for(int s=128;s>0;s>>=1){ if(t<s){ shA[t]+=shA[t+s]; shB[t]+=shB[t+s]; } __syncthreads(); }
  if(t==0){ float a=shA[0]; wx[c]=gnA[c]*a; we[c]=shB[0]; atomicAdd(aconst, gnB[c]*a); }
}

// a[i] = sum_c src[i,c]*wv[c] (+ cst)
__global__ __launch_bounds__(64) void k_matvec(const float* __restrict__ src, const float* __restrict__ wv,
    const float* __restrict__ cst, float* __restrict__ out){
  int i = blockIdx.x, l = threadIdx.x;
  float s=0.f;
  for(int c=l;c<FD;c+=64) s += src[(size_t)i*FD+c]*wv[c];
  for(int o=32;o;o>>=1) s += __shfl_down(s,o);
  if(l==0) out[i] = s + (cst ? cst[0] : 0.f);
}

// ---------------- alpha / segment softmax ----------------
__global__ void k_alpha1(const int* __restrict__ row, const int* __restrict__ col,
                         const float* __restrict__ ax, const float* __restrict__ ae,
                         float* __restrict__ araw, unsigned* __restrict__ segmax){
  int e = blockIdx.x*256 + threadIdx.x;
  if(e>=NNZE) return;
  float a = ax[row[e]] + ae[col[e]];
  a = (a>=0.f) ? a : 0.2f*a;
  araw[e]=a;
  atomicMax(&segmax[col[e]], fmapu(a));
}
__global__ void k_alpha2(const int* __restrict__ col, const float* __restrict__ araw,
                         const unsigned* __restrict__ segmax,
                         float* __restrict__ eexp, float* __restrict__ esum){
  int e = blockIdx.x*256 + threadIdx.x;
  if(e>=NNZE) return;
  float m = funmapu(segmax[col[e]]);
  float x = expf(araw[e]-m);
  eexp[e]=x;
  atomicAdd(&esum[col[e]], x);
}
__global__ void k_alpha3(const int* __restrict__ col, const float* __restrict__ eexp,
                         const float* __restrict__ esum, float* __restrict__ asm_){
  int e = blockIdx.x*256 + threadIdx.x;
  if(e>=NNZE) return;
  asm_[e] = eexp[e] / (esum[col[e]] + 1e-16f);
}

// ---------------- segment gather-sum over 768-wide rows ----------------
__global__ __launch_bounds__(256) void k_seg_gather(const float* __restrict__ src,
    const int* __restrict__ offs, const int* __restrict__ eids,
    const int* __restrict__ gidx, const float* __restrict__ alpha_sm,
    const float* __restrict__ segscale, const float* __restrict__ bias, float slope,
    float* __restrict__ dst){
  int c = blockIdx.x, t = threadIdx.x;
  int beg = offs[c], end = offs[c+1];
  float scale = segscale[c];
  __shared__ float wsh[256]; __shared__ int rsh[256];
  float a0=0.f,a1=0.f,a2=0.f;
  for(int base=beg; base<end; base+=256){
    int idx = base+t;
    if(idx<end){ int e=eids[idx]; wsh[t]=alpha_sm[e]; rsh[t]=gidx[e]; }
    __syncthreads();
    int cnt = min(256, end-base);
    for(int j=0;j<cnt;j++){
      float wj = wsh[j];
      const float* r = src + (size_t)rsh[j]*FD;
      a0 += wj*r[t]; a1 += wj*r[t+256]; a2 += wj*r[t+512];
    }
    __syncthreads();
  }
  a0*=scale; a1*=scale; a2*=scale;
  if(bias){
    a0+=bias[t]; a1+=bias[t+256]; a2+=bias[t+512];
    a0=(a0>=0.f)?a0:slope*a0; a1=(a1>=0.f)?a1:slope*a1; a2=(a2>=0.f)?a2:slope*a2;
  }
  dst[(size_t)c*FD+t]=a0; dst[(size_t)c*FD+t+256]=a1; dst[(size_t)c*FD+t+512]=a2;
}

// ---------------- catT build ----------------
__global__ __launch_bounds__(256) void k_build_catT(const float* __restrict__ x,
    const float* __restrict__ o1, const float* __restrict__ o2, short* __restrict__ catT){
  __shared__ float tile[32][33];
  int i0 = blockIdx.x*32, d0 = blockIdx.y*32;
  int tx = threadIdx.x, ty = threadIdx.y;   // 32 x 8
  const float* src; int dof, ld;
  if(d0 < FD){ src=x; dof=d0; ld=FD; }
  else if(d0 < FD+HIDD){ src=o1; dof=d0-FD; ld=HIDD; }
  else { src=o2; dof=d0-FD-HIDD; ld=HIDD; }
  for(int yy=ty; yy<32; yy+=8)
    tile[yy][tx] = src[(size_t)(i0+yy)*ld + dof + tx];
  __syncthreads();
  for(int yy=ty; yy<32; yy+=8)
    catT[(size_t)(d0+yy)*NN + i0 + tx] = f2bf(tile[tx][yy]);
}

// ---------------- attention mega-GEMM, m97 LDS structure + fused relu*W2 epilogue ----
// 768 blocks: swizzled so the 12 m-replicas of an n-tile-class share an XCD's L2.
__global__ __launch_bounds__(256) void attn_gemm_lds(const short* __restrict__ catT,
    const short* __restrict__ W1b, const float* __restrict__ b1, const float* __restrict__ W2,
    float* __restrict__ score_pre){
  const int K = NN;
  __shared__ __align__(16) short As[128*32];
  __shared__ __align__(16) short Bs[128*32];
  int id = blockIdx.x;             // 0..767
  int cc = id&7, g = id>>3;
  int m_idx = g%12;                // 0..11
  int n_idx = (g/12)*8 + cc;       // 0..63
  int m0 = m_idx*128, n0 = n_idx*128;
  int t = threadIdx.x;
  int w = t>>6, l = t&63;
  int wm = w>>1, wn = w&1;
  int li = l&15, q = l>>4;
  const short* Ag = catT + (size_t)(m0 + w*16 + (l>>2))*K + (l&3)*8;
  const short* Bg = W1b + (size_t)(n0 + w*16 + (l>>2))*K + (l&3)*8;
  short* Asl = &As[(w*16)*32];
  short* Bsl = &Bs[(w*16)*32];
  f32x4 acc[4][4];
  #pragma unroll
  for(int i=0;i<4;i++)
    #pragma unroll
    for(int j=0;j<4;j++) acc[i][j] = (f32x4){0.f,0.f,0.f,0.f};
  for(int k0=0;k0<K;k0+=32){
    async_copy16(Asl,          Ag + k0);
    async_copy16(Asl + 64*32,  Ag + (size_t)64*K + k0);
    async_copy16(Bsl,          Bg + k0);
    async_copy16(Bsl + 64*32,  Bg + (size_t)64*K + k0);
    __syncthreads();
    bf16x8 a[4], b[4];
    #pragma unroll
    for(int i=0;i<4;i++) a[i] = *(const bf16x8*)&As[(wm*64 + i*16 + li)*32 + q*8];
    #pragma unroll
    for(int j=0;j<4;j++) b[j] = *(const bf16x8*)&Bs[(wn*64 + j*16 + li)*32 + q*8];
    #pragma unroll
    for(int i=0;i<4;i++)
      #pragma unroll
      for(int j=0;j<4;j++)
        acc[i][j] = __builtin_amdgcn_mfma_f32_16x16x32_bf16(a[i], b[j], acc[i][j], 0, 0, 0);
    __syncthreads();
  }
  float w2v[4], b1v[4];
  #pragma unroll
  for(int j=0;j<4;j++){ int gn = n0 + wn*64 + j*16 + li; w2v[j]=W2[gn]; b1v[j]=b1[gn]; }
  #pragma unroll
  for(int i=0;i<4;i++){
    #pragma unroll
    for(int r=0;r<4;r++){
      float s=0.f;
      #pragma unroll
      for(int j=0;j<4;j++){
        float v = acc[i][j][r] + b1v[j];
        v = v>0.f ? v : 0.f;
        s += v*w2v[j];
      }
      s += __shfl_xor(s,1); s += __shfl_xor(s,2); s += __shfl_xor(s,4); s += __shfl_xor(s,8);
      if(li==0) atomicAdd(&score_pre[m0 + wm*64 + i*16 + q*4 + r], s);
    }
  }
}

// fallback (on-the-fly f32->bf16 cvt) if ws can't hold W1b
__global__ __launch_bounds__(256) void attn_gemm_f32(const short* __restrict__ catT,
    const float* __restrict__ W1, const float* __restrict__ b1, const float* __restrict__ W2,
    float* __restrict__ score_pre){
  const int K = NN;
  int lane = threadIdx.x & 63;
  int wv   = threadIdx.x >> 6;
  int m0 = (blockIdx.x*4 + wv)*64;
  int n0 = blockIdx.y*64;
  int li = lane & 15, q = lane >> 4;
  const short* Ab = catT + (size_t)(m0+li)*K + q*8;
  const float* Bb = W1 + (size_t)(n0+li)*K + q*8;
  f32x4 acc[4][4];
  #pragma unroll
  for(int i=0;i<4;i++)
    #pragma unroll
    for(int j=0;j<4;j++) acc[i][j] = (f32x4){0.f,0.f,0.f,0.f};
  for(int k0=0;k0<K;k0+=32){
    bf16x8 a[4], b[4];
    #pragma unroll
    for(int i=0;i<4;i++) a[i] = *(const bf16x8*)(Ab + (size_t)i*16*K + k0);
    #pragma unroll
    for(int j=0;j<4;j++){
      const float* p = Bb + (size_t)j*16*K + k0;
      float4 f0 = *(const float4*)p;
      float4 f1 = *(const float4*)(p+4);
      bf16x8 t;
      t[0]=f2bf(f0.x); t[1]=f2bf(f0.y); t[2]=f2bf(f0.z); t[3]=f2bf(f0.w);
      t[4]=f2bf(f1.x); t[5]=f2bf(f1.y); t[6]=f2bf(f1.z); t[7]=f2bf(f1.w);
      b[j]=t;
    }
    #pragma unroll
    for(int i=0;i<4;i++)
      #pragma unroll
      for(int j=0;j<4;j++)
        acc[i][j] = __builtin_amdgcn_mfma_f32_16x16x32_bf16(a[i], b[j], acc[i][j], 0, 0, 0);
  }
  float w2v[4], b1v[4];
  #pragma unroll
  for(int j=0;j<4;j++){ int gn=n0+j*16+li; w2v[j]=W2[gn]; b1v[j]=b1[gn]; }
  #pragma unroll
  for(int i=0;i<4;i++){
    #pragma unroll
    for(int r=0;r<4;r++){
      float s=0.f;
      #pragma unroll
      for(int j=0;j<4;j++){
        float v = acc[i][j][r] + b1v[j];
        v = v>0.f ? v : 0.f;
        s += v*w2v[j];
      }
      s += __shfl_xor(s,1); s += __shfl_xor(s,2); s += __shfl_xor(s,4); s += __shfl_xor(s,8);
      if(li==0) atomicAdd(&score_pre[m0 + i*16 + q*4 + r], s);
    }
  }
}

// ---------------- score finalize ----------------
__global__ void k_score(const float* __restrict__ pre, const float* __restrict__ b2,
                        const float* __restrict__ center, const float* __restrict__ clsW,
                        float* __restrict__ sw){
  int d = blockIdx.x*256 + threadIdx.x;
  if(d>=DCATD) return;
  float sc = pre[d] + b2[0];
  sc = 1.f/(1.f+expf(-sc));
  sc -= center[d];
  #pragma unroll
  for(int o=0;o<10;o++) sw[d*10+o] = sc * clsW[(size_t)o*DCATD + d];
}

// ---------------- final ----------------
__global__ __launch_bounds__(64) void k_final(const float* __restrict__ x, const float* __restrict__ o1,
    const float* __restrict__ o2, const float* __restrict__ sw, const float* __restrict__ clsb,
    float* __restrict__ out){
  int i = blockIdx.x, l = threadIdx.x;
  float acc[10];
  #pragma unroll
  for(int o=0;o<10;o++) acc[o]=0.f;
  for(int d=l; d<DCATD; d+=64){
    float v = (d<FD) ? x[(size_t)i*FD + d]
            : (d<FD+HIDD) ? o1[(size_t)i*HIDD + d-FD]
            : o2[(size_t)i*HIDD + d-FD-HIDD];
    const float* s = sw + (size_t)d*10;
    #pragma unroll
    for(int o=0;o<10;o++) acc[o] += v*s[o];
  }
  #pragma unroll
  for(int o=0;o<10;o++){
    float t = acc[o];
    for(int off=32;off;off>>=1) t += __shfl_down(t,off);
    if(l==0) out[(size_t)i*10 + o] = t + clsb[o];
  }
}

extern "C" void kernel_launch(void* const* d_in, const int* in_sizes, int n_in,
                              void* d_out, int out_size, void* d_ws, size_t ws_size,
                              hipStream_t stream) {
  const float* x      = (const float*)d_in[0];
  const int*   ei     = (const int*)d_in[1];
  const float* eattr  = (const float*)d_in[2];
  const float* gn1_w  = (const float*)d_in[3];
  const float* gn1_b  = (const float*)d_in[4];
  const float* gn1_ms = (const float*)d_in[5];
  const float* gn2_w  = (const float*)d_in[6];
  const float* gn2_b  = (const float*)d_in[7];
  const float* gn2_ms = (const float*)d_in[8];
  const float* hg1_W  = (const float*)d_in[9];
  const float* hg1_att= (const float*)d_in[10];
  const float* hg1_b  = (const float*)d_in[11];
  const float* hg2_W  = (const float*)d_in[12];
  const float* hg2_att= (const float*)d_in[13];
  const float* hg2_b  = (const float*)d_in[14];
  const float* fc1_W  = (const float*)d_in[15];
  const float* fc1_b  = (const float*)d_in[16];
  const float* fc2_W  = (const float*)d_in[17];
  const float* fc2_b  = (const float*)d_in[18];
  const float* attn_W1= (const float*)d_in[19];
  const float* attn_b1= (const float*)d_in[20];
  const float* attn_W2= (const float*)d_in[21];
  const float* attn_b2= (const float*)d_in[22];
  const float* cls_W  = (const float*)d_in[23];
  const float* cls_b  = (const float*)d_in[24];
  const float* center = (const float*)d_in[25];
  float* out = (float*)d_out;

  const int* row = ei;
  const int* col = ei + NNZE;

  char* w = (char*)d_ws;
  size_t off = 0;
  auto alloc = [&](size_t bytes)->void*{
    off = (off + 255) & ~(size_t)255;
    void* p = w + off;
    off += bytes;
    return p;
  };
  float* xt    = (float*)alloc((size_t)NN*FD*4);
  float* ef    = (float*)alloc((size_t)NN*FD*4);     // later aliased as catT (bf16)
  float* h     = (float*)alloc((size_t)NN*FD*4);
  float* out1  = (float*)alloc((size_t)NN*HIDD*4);
  float* out2  = (float*)alloc((size_t)NN*HIDD*4);
  short* inb   = (short*)alloc((size_t)NN*FD*2);
  short* wb    = (short*)alloc((size_t)FD*FD*2);
  int* cnt_col = (int*)alloc(NN*4);
  int* cnt_row = (int*)alloc(NN*4);
  int* col_off = (int*)alloc((NN+1)*4);
  int* row_off = (int*)alloc((NN+1)*4);
  int* col_cur = (int*)alloc(NN*4);
  int* row_cur = (int*)alloc(NN*4);
  int* ceids   = (int*)alloc(NNZE*4);
  int* reids   = (int*)alloc(NNZE*4);
  float* Bn    = (float*)alloc(NN*4);
  float* Dn    = (float*)alloc(NN*4);
  float* a_x   = (float*)alloc(NN*4);
  float* a_e   = (float*)alloc(NN*4);
  float* araw  = (float*)alloc(NNZE*4);
  float* eexp  = (float*)alloc(NNZE*4);
  float* asm_  = (float*)alloc(NNZE*4);
  unsigned* segmax = (unsigned*)alloc(NN*4);
  float* esum  = (float*)alloc(NN*4);
  float* gsum  = (float*)alloc(FD*4);
  float* gssq  = (float*)alloc(FD*4);
  float* gnA   = (float*)alloc(FD*4);
  float* gnB   = (float*)alloc(FD*4);
  float* wx    = (float*)alloc(FD*4);
  float* we    = (float*)alloc(FD*4);
  float* aconst= (float*)alloc(256);
  float* score_pre = (float*)alloc(DCATD*4);
  float* sw    = (float*)alloc(DCATD*10*4);
  short* catT  = (short*)ef;   // alias: ef dead by the time catT is built
  // W1 bf16 copy — only if workspace has room (134 MB)
  size_t off_before_w1b = off;
  short* W1b   = (short*)alloc((size_t)NN*NN*2);
  bool use_w1b = (off <= ws_size);
  if(!use_w1b) off = off_before_w1b;
  (void)n_in; (void)in_sizes; (void)out_size;

  // ---- CSR build ----
  hipMemsetAsync(cnt_col, 0, NN*4, stream);
  hipMemsetAsync(cnt_row, 0, NN*4, stream);
  k_hist<<<NNZE/256, 256, 0, stream>>>(row, col, cnt_row, cnt_col);
  k_scan8192<<<1, 1024, 0, stream>>>(cnt_col, col_off, col_cur);
  k_scan8192<<<1, 1024, 0, stream>>>(cnt_row, row_off, row_cur);
  k_scatter<<<NNZE/256, 256, 0, stream>>>(row, col, col_cur, row_cur, ceids, reids);
  k_deg<<<NN/256, 256, 0, stream>>>(cnt_col, cnt_row, Bn, Dn);

  // convert attn_W1 to bf16 early
  if(use_w1b)
    k_cvt8<<<(NN*(size_t)NN)/8/256, 256, 0, stream>>>(attn_W1, W1b);

  for(int layer=0; layer<2; layer++){
    const float* src_feat = (layer==0) ? x : h;
    const float* gW   = (layer==0) ? gn1_w  : gn2_w;
    const float* gB   = (layer==0) ? gn1_b  : gn2_b;
    const float* gMS  = (layer==0) ? gn1_ms : gn2_ms;
    const float* hgW  = (layer==0) ? hg1_W  : hg2_W;
    const float* hgAtt= (layer==0) ? hg1_att: hg2_att;
    const float* hgB  = (layer==0) ? hg1_b  : hg2_b;
    const float* fcW  = (layer==0) ? fc1_W  : fc2_W;
    const float* fcB  = (layer==0) ? fc1_b  : fc2_b;
    float* fout       = (layer==0) ? out1   : out2;

    hipMemsetAsync(gsum, 0, FD*4, stream);
    hipMemsetAsync(gssq, 0, FD*4, stream);
    k_colstats<<<dim3(3,32), 256, 0, stream>>>(src_feat, gsum, gssq);
    k_gn_fin<<<3, 256, 0, stream>>>(gsum, gssq, gW, gB, gMS, gnA, gnB);

    hipMemsetAsync(aconst, 0, 4, stream);
    k_watt<<<FD, 256, 0, stream>>>(hgW, hgAtt, gnA, gnB, wx, we, aconst);
    k_matvec<<<NN, 64, 0, stream>>>(src_feat, wx, aconst, a_x);
    k_matvec<<<NN, 64, 0, stream>>>(eattr, we, nullptr, a_e);

    k_affcast<<<(NN*FD)/256, 256, 0, stream>>>(src_feat, gnA, gnB, inb);
    k_cast_bf16<<<(FD*FD)/256, 256, 0, stream>>>(hgW, wb, FD*FD);
    gemm_lds<<<dim3(FD/128, NN/128), 256, 0, stream>>>(inb, wb, xt, NN, FD, FD, nullptr, 1.f);

    hipMemsetAsync(segmax, 0, NN*4, stream);
    hipMemsetAsync(esum, 0, NN*4, stream);
    k_alpha1<<<NNZE/256, 256, 0, stream>>>(row, col, a_x, a_e, araw, segmax);
    k_alpha2<<<NNZE/256, 256, 0, stream>>>(col, araw, segmax, eexp, esum);
    k_alpha3<<<NNZE/256, 256, 0, stream>>>(col, eexp, esum, asm_);

    k_seg_gather<<<NN, 256, 0, stream>>>(xt, col_off, ceids, row, asm_, Bn, nullptr, 1.f, ef);
    k_seg_gather<<<NN, 256, 0, stream>>>(ef, row_off, reids, col, asm_, Dn, hgB, 0.01f, h);

    k_cast_bf16<<<(NN*FD)/256, 256, 0, stream>>>(h, inb, NN*FD);
    k_cast_bf16<<<(HIDD*FD)/256, 256, 0, stream>>>(fcW, wb, HIDD*FD);
    gemm_lds<<<dim3(HIDD/128, NN/128), 256, 0, stream>>>(inb, wb, fout, NN, HIDD, FD, fcB, 0.01f);
  }

  // ---- attention over cat = [x, out1, out2] ----
  k_build_catT<<<dim3(NN/32, DCATD/32), dim3(32,8), 0, stream>>>(x, out1, out2, catT);
  hipMemsetAsync(score_pre, 0, DCATD*4, stream);
  if(use_w1b)
    attn_gemm_lds<<<768, 256, 0, stream>>>(catT, W1b, attn_b1, attn_W2, score_pre);
  else
    attn_gemm_f32<<<dim3(DCATD/256, NN/64), 256, 0, stream>>>(catT, attn_W1, attn_b1, attn_W2, score_pre);
  k_score<<<DCATD/256, 256, 0, stream>>>(score_pre, attn_b2, center, cls_W, sw);
  k_final<<<NN, 64, 0, stream>>>(x, out1, out2, sw, cls_b, out);
}

// Round 4
// 1225.793 us; speedup vs baseline: 1.7029x; 1.0846x over previous
//
#include <hip/hip_runtime.h>
#include <cstddef>

#define NN 8192
#define FD 768
#define HIDD 384
#define NNZE 131072
#define DCATD 1536

typedef short bf16x8 __attribute__((ext_vector_type(8)));
typedef float f32x4 __attribute__((ext_vector_type(4)));

__device__ __forceinline__ short f2bf(float f){
  unsigned u = __float_as_uint(f);
  unsigned r = u + 0x7FFFu + ((u>>16)&1u);   // RNE
  return (short)(r>>16);
}

// async global -> LDS, 16B per lane. lds ptr wave-uniform; HW scatters lane*16.
__device__ __forceinline__ void async_copy16(void* lds, const void* g){
  __builtin_amdgcn_global_load_lds((__attribute__((address_space(1))) void*)g,
                                   (__attribute__((address_space(3))) void*)lds, 16, 0, 0);
}

// ---------------- CSR build ----------------
__global__ void k_hist(const int* __restrict__ row, const int* __restrict__ col,
                       int* __restrict__ cr, int* __restrict__ cc){
  int e = blockIdx.x*256 + threadIdx.x;
  if(e >= NNZE) return;
  atomicAdd(&cc[col[e]], 1);
  atomicAdd(&cr[row[e]], 1);
}

// 2 blocks: block 0 scans col counts (-> col_off/cur + Bn), block 1 row (-> row_off/cur + Dn)
__global__ __launch_bounds__(1024) void k_scan2(const int* __restrict__ cnt_col,
    const int* __restrict__ cnt_row,
    int* __restrict__ col_off, int* __restrict__ row_off,
    int* __restrict__ col_cur, int* __restrict__ row_cur,
    float* __restrict__ Bn, float* __restrict__ Dn){
  const int* cnt = (blockIdx.x==0) ? cnt_col : cnt_row;
  int* offs = (blockIdx.x==0) ? col_off : row_off;
  int* cur  = (blockIdx.x==0) ? col_cur : row_cur;
  float* rec= (blockIdx.x==0) ? Bn : Dn;
  __shared__ int part[1024];
  int t = threadIdx.x;
  int v[8]; int s = 0;
  #pragma unroll
  for(int j=0;j<8;j++){ v[j]=cnt[t*8+j]; s+=v[j]; }
  part[t]=s; __syncthreads();
  for(int d=1; d<1024; d<<=1){
    int mine = part[t];
    int add = (t>=d)? part[t-d] : 0;
    __syncthreads();
    part[t] = mine + add;
    __syncthreads();
  }
  int excl = part[t]-s;
  #pragma unroll
  for(int j=0;j<8;j++){
    offs[t*8+j]=excl; cur[t*8+j]=excl; excl+=v[j];
    rec[t*8+j] = (v[j]>0) ? 1.f/(float)v[j] : 0.f;
  }
  if(t==1023) offs[8192]=excl;
}

__global__ void k_scatter(const int* __restrict__ row, const int* __restrict__ col,
                          int* __restrict__ ccur, int* __restrict__ rcur,
                          int* __restrict__ ceids, int* __restrict__ reids){
  int e = blockIdx.x*256 + threadIdx.x;
  if(e >= NNZE) return;
  int p = atomicAdd(&ccur[col[e]],1); ceids[p]=e;
  int q = atomicAdd(&rcur[row[e]],1); reids[q]=e;
}

// ---------------- all weight casts in ONE dispatch ----------------
// blocks [0,nW1): W1 (2048 elems each); then 288 hg1W, 288 hg2W, 144 fc1W, 144 fc2W
__global__ __launch_bounds__(256) void k_cvt_all(int nW1,
    const float* __restrict__ W1, short* __restrict__ W1b,
    const float* __restrict__ hg1W, short* __restrict__ wb1,
    const float* __restrict__ hg2W, short* __restrict__ wb2,
    const float* __restrict__ fc1W, short* __restrict__ fwb1,
    const float* __restrict__ fc2W, short* __restrict__ fwb2){
  int b = blockIdx.x;
  const float* s; short* d; size_t base;
  if(b < nW1){ s=W1; d=W1b; base=(size_t)b*2048; }
  else {
    int r = b - nW1;
    if(r<288){ s=hg1W; d=wb1; base=(size_t)r*2048; }
    else if(r<576){ s=hg2W; d=wb2; base=(size_t)(r-288)*2048; }
    else if(r<720){ s=fc1W; d=fwb1; base=(size_t)(r-576)*2048; }
    else { s=fc2W; d=fwb2; base=(size_t)(r-720)*2048; }
  }
  size_t i = base + (size_t)threadIdx.x*8;
  float4 f0 = *(const float4*)(s+i);
  float4 f1 = *(const float4*)(s+i+4);
  bf16x8 t;
  t[0]=f2bf(f0.x); t[1]=f2bf(f0.y); t[2]=f2bf(f0.z); t[3]=f2bf(f0.w);
  t[4]=f2bf(f1.x); t[5]=f2bf(f1.y); t[6]=f2bf(f1.z); t[7]=f2bf(f1.w);
  *(bf16x8*)(d+i) = t;
}

// ---------------- GraphNorm stats ----------------
__global__ __launch_bounds__(256) void k_colstats(const float* __restrict__ src,
                                                  float* __restrict__ gs, float* __restrict__ gss){
  int col = blockIdx.x*256 + threadIdx.x;     // 0..767
  int r0 = blockIdx.y*256;
  float s1=0.f, s2=0.f;
  for(int r=0;r<256;r++){
    float v = src[(size_t)(r0+r)*FD + col];
    s1+=v; s2+=v*v;
  }
  atomicAdd(&gs[col], s1);
  atomicAdd(&gss[col], s2);
}

// per-column: W^T·att dots  +  GraphNorm affine coeffs (gn_fin fused)
__global__ __launch_bounds__(256) void k_watt(const float* __restrict__ W, const float* __restrict__ att,
    const float* __restrict__ gs, const float* __restrict__ gss,
    const float* __restrict__ w_, const float* __restrict__ b_, const float* __restrict__ ms_,
    float* __restrict__ gnA, float* __restrict__ gnB,
    float* __restrict__ wxr, float* __restrict__ we){
  int c = blockIdx.x; int t = threadIdx.x;
  float sA=0.f, sB=0.f;
  for(int f=t; f<FD; f+=256){
    float w = W[(size_t)f*FD + c];
    sA += w*att[f];
    sB += w*att[FD+f];
  }
  __shared__ float shA[256], shB[256];
  shA[t]=sA; shB[t]=sB; __syncthreads();
  for(int s=128;s>0;s>>=1){ if(t<s){ shA[t]+=shA[t+s]; shB[t]+=shB[t+s]; } __syncthreads(); }
  if(t==0){
    float mean = gs[c]*(1.f/(float)NN);
    float ex2  = gss[c]*(1.f/(float)NN);
    float ctr  = ms_[c]*mean;
    float var  = ex2 - 2.f*ctr*mean + ctr*ctr;
    float a    = w_[c] / sqrtf(var + 1e-5f);
    gnA[c]=a; gnB[c]=b_[c] - a*ctr;
    wxr[c]=shA[0]; we[c]=shB[0];
  }
}

// a[i] = sum_c src[i,c]*wv[c]   (a_e path)
__global__ __launch_bounds__(64) void k_matvec(const float* __restrict__ src, const float* __restrict__ wv,
    float* __restrict__ out){
  int i = blockIdx.x, l = threadIdx.x;
  float s=0.f;
  for(int c=l;c<FD;c+=64) s += src[(size_t)i*FD+c]*wv[c];
  for(int o=32;o;o>>=1) s += __shfl_down(s,o);
  if(l==0) out[i] = s;
}

// normalized bf16 row + dot with wxr in one pass (affcast + matvec a_x fused)
__global__ __launch_bounds__(256) void k_affdot(const float* __restrict__ src,
    const float* __restrict__ A, const float* __restrict__ B, const float* __restrict__ wxr,
    short* __restrict__ dstb, float* __restrict__ ax){
  int i = blockIdx.x, t = threadIdx.x;
  float p = 0.f;
  #pragma unroll
  for(int k=0;k<3;k++){
    int c = t + k*256;
    float v = A[c]*src[(size_t)i*FD+c] + B[c];
    dstb[(size_t)i*FD+c] = f2bf(v);
    p += v*wxr[c];
  }
  __shared__ float sh[256];
  sh[t]=p; __syncthreads();
  for(int s=128;s>0;s>>=1){ if(t<s) sh[t]+=sh[t+s]; __syncthreads(); }
  if(t==0) ax[i]=sh[0];
}

// ---------------- m97-style LDS-staged bf16 NT GEMM ----------------
__global__ __launch_bounds__(256) void gemm_lds(const short* __restrict__ A, const short* __restrict__ B,
    float* __restrict__ C, int M, int N, int K,
    const float* __restrict__ bias, float slope){
  __shared__ __align__(16) short As[128*32];
  __shared__ __align__(16) short Bs[128*32];
  int t = threadIdx.x;
  int w = t>>6, l = t&63;
  int m0 = blockIdx.y*128, n0 = blockIdx.x*128;
  int wm = w>>1, wn = w&1;
  int li = l&15, q = l>>4;
  const short* Ag = A + (size_t)(m0 + w*16 + (l>>2))*K + (l&3)*8;
  const short* Bg = B + (size_t)(n0 + w*16 + (l>>2))*K + (l&3)*8;
  short* Asl = &As[(w*16)*32];
  short* Bsl = &Bs[(w*16)*32];
  f32x4 acc[4][4];
  #pragma unroll
  for(int i=0;i<4;i++)
    #pragma unroll
    for(int j=0;j<4;j++) acc[i][j] = (f32x4){0.f,0.f,0.f,0.f};
  for(int k0=0;k0<K;k0+=32){
    async_copy16(Asl,          Ag + k0);
    async_copy16(Asl + 64*32,  Ag + (size_t)64*K + k0);
    async_copy16(Bsl,          Bg + k0);
    async_copy16(Bsl + 64*32,  Bg + (size_t)64*K + k0);
    __syncthreads();
    bf16x8 a[4], b[4];
    #pragma unroll
    for(int i=0;i<4;i++) a[i] = *(const bf16x8*)&As[(wm*64 + i*16 + li)*32 + q*8];
    #pragma unroll
    for(int j=0;j<4;j++) b[j] = *(const bf16x8*)&Bs[(wn*64 + j*16 + li)*32 + q*8];
    #pragma unroll
    for(int i=0;i<4;i++)
      #pragma unroll
      for(int j=0;j<4;j++)
        acc[i][j] = __builtin_amdgcn_mfma_f32_16x16x32_bf16(a[i], b[j], acc[i][j], 0, 0, 0);
    __syncthreads();
  }
  #pragma unroll
  for(int i=0;i<4;i++){
    int gm = m0 + wm*64 + i*16 + q*4;
    #pragma unroll
    for(int j=0;j<4;j++){
      int gn = n0 + wn*64 + j*16 + li;
      float bv = bias ? bias[gn] : 0.f;
      #pragma unroll
      for(int r=0;r<4;r++){
        float vv = acc[i][j][r] + bv;
        vv = (vv>=0.f) ? vv : vv*slope;
        C[(size_t)(gm+r)*N + gn] = vv;
      }
    }
  }
}

// ---------------- per-segment softmax via CSR (replaces alpha1/2/3 + 2 memsets) -------
__global__ __launch_bounds__(256) void k_softmax_seg(const int* __restrict__ offs,
    const int* __restrict__ eids, const int* __restrict__ row,
    const float* __restrict__ ax, const float* __restrict__ ae, float* __restrict__ asm_){
  int seg = blockIdx.x*4 + (threadIdx.x>>6);
  int l = threadIdx.x & 63;
  int beg = offs[seg], end = offs[seg+1];
  if(beg >= end) return;                 // wave-uniform
  float aev = ae[seg];
  float m = -1e30f;
  for(int idx=beg+l; idx<end; idx+=64){
    int e = eids[idx];
    float a = ax[row[e]] + aev; a = (a>=0.f)?a:0.2f*a;
    m = fmaxf(m, a);
  }
  #pragma unroll
  for(int o=1;o<64;o<<=1) m = fmaxf(m, __shfl_xor(m,o));
  float s = 0.f;
  for(int idx=beg+l; idx<end; idx+=64){
    int e = eids[idx];
    float a = ax[row[e]] + aev; a = (a>=0.f)?a:0.2f*a;
    s += expf(a-m);
  }
  #pragma unroll
  for(int o=1;o<64;o<<=1) s += __shfl_xor(s,o);
  float inv = 1.f/(s + 1e-16f);
  for(int idx=beg+l; idx<end; idx+=64){
    int e = eids[idx];
    float a = ax[row[e]] + aev; a = (a>=0.f)?a:0.2f*a;
    asm_[e] = expf(a-m)*inv;
  }
}

// ---------------- segment gather-sum (float4, 2-edge unroll, optional bf16 dual-out) --
__global__ __launch_bounds__(192) void k_seg_gather(const float* __restrict__ src,
    const int* __restrict__ offs, const int* __restrict__ eids,
    const int* __restrict__ gidx, const float* __restrict__ alpha_sm,
    const float* __restrict__ segscale, const float* __restrict__ bias, float slope,
    float* __restrict__ dst, short* __restrict__ dstb){
  int c = blockIdx.x, t = threadIdx.x;   // t in [0,192), col4 = t
  int beg = offs[c], end = offs[c+1];
  float scale = segscale[c];
  __shared__ float wsh[192]; __shared__ int rsh[192];
  float4 acc = {0.f,0.f,0.f,0.f};
  for(int base=beg; base<end; base+=192){
    int idx = base+t;
    if(idx<end){ int e=eids[idx]; wsh[t]=alpha_sm[e]; rsh[t]=gidx[e]; }
    __syncthreads();
    int cnt = min(192, end-base);
    int j=0;
    for(; j+1<cnt; j+=2){
      float w0=wsh[j], w1=wsh[j+1];
      float4 v0 = *((const float4*)(src + (size_t)rsh[j]*FD) + t);
      float4 v1 = *((const float4*)(src + (size_t)rsh[j+1]*FD) + t);
      acc.x += w0*v0.x + w1*v1.x;
      acc.y += w0*v0.y + w1*v1.y;
      acc.z += w0*v0.z + w1*v1.z;
      acc.w += w0*v0.w + w1*v1.w;
    }
    if(j<cnt){
      float w0=wsh[j];
      float4 v0 = *((const float4*)(src + (size_t)rsh[j]*FD) + t);
      acc.x += w0*v0.x; acc.y += w0*v0.y; acc.z += w0*v0.z; acc.w += w0*v0.w;
    }
    __syncthreads();
  }
  acc.x*=scale; acc.y*=scale; acc.z*=scale; acc.w*=scale;
  if(bias){
    float4 bv = *((const float4*)bias + t);
    acc.x+=bv.x; acc.y+=bv.y; acc.z+=bv.z; acc.w+=bv.w;
    acc.x=(acc.x>=0.f)?acc.x:slope*acc.x;
    acc.y=(acc.y>=0.f)?acc.y:slope*acc.y;
    acc.z=(acc.z>=0.f)?acc.z:slope*acc.z;
    acc.w=(acc.w>=0.f)?acc.w:slope*acc.w;
  }
  *((float4*)(dst + (size_t)c*FD) + t) = acc;
  if(dstb){
    short4 o; o.x=f2bf(acc.x); o.y=f2bf(acc.y); o.z=f2bf(acc.z); o.w=f2bf(acc.w);
    *((short4*)(dstb + (size_t)c*FD) + t) = o;
  }
}

// ---------------- catT build ----------------
__global__ __launch_bounds__(256) void k_build_catT(const float* __restrict__ x,
    const float* __restrict__ o1, const float* __restrict__ o2, short* __restrict__ catT){
  __shared__ float tile[32][33];
  int i0 = blockIdx.x*32, d0 = blockIdx.y*32;
  int tx = threadIdx.x, ty = threadIdx.y;   // 32 x 8
  const float* src; int dof, ld;
  if(d0 < FD){ src=x; dof=d0; ld=FD; }
  else if(d0 < FD+HIDD){ src=o1; dof=d0-FD; ld=HIDD; }
  else { src=o2; dof=d0-FD-HIDD; ld=HIDD; }
  for(int yy=ty; yy<32; yy+=8)
    tile[yy][tx] = src[(size_t)(i0+yy)*ld + dof + tx];
  __syncthreads();
  for(int yy=ty; yy<32; yy+=8)
    catT[(size_t)(d0+yy)*NN + i0 + tx] = f2bf(tile[tx][yy]);
}

// ---------------- attention mega-GEMM (m97 LDS structure, XCD swizzle) ----------------
__global__ __launch_bounds__(256) void attn_gemm_lds(const short* __restrict__ catT,
    const short* __restrict__ W1b, const float* __restrict__ b1, const float* __restrict__ W2,
    float* __restrict__ score_pre){
  const int K = NN;
  __shared__ __align__(16) short As[128*32];
  __shared__ __align__(16) short Bs[128*32];
  int id = blockIdx.x;             // 0..767
  int cc = id&7, g = id>>3;
  int m_idx = g%12;
  int n_idx = (g/12)*8 + cc;
  int m0 = m_idx*128, n0 = n_idx*128;
  int t = threadIdx.x;
  int w = t>>6, l = t&63;
  int wm = w>>1, wn = w&1;
  int li = l&15, q = l>>4;
  const short* Ag = catT + (size_t)(m0 + w*16 + (l>>2))*K + (l&3)*8;
  const short* Bg = W1b + (size_t)(n0 + w*16 + (l>>2))*K + (l&3)*8;
  short* Asl = &As[(w*16)*32];
  short* Bsl = &Bs[(w*16)*32];
  f32x4 acc[4][4];
  #pragma unroll
  for(int i=0;i<4;i++)
    #pragma unroll
    for(int j=0;j<4;j++) acc[i][j] = (f32x4){0.f,0.f,0.f,0.f};
  for(int k0=0;k0<K;k0+=32){
    async_copy16(Asl,          Ag + k0);
    async_copy16(Asl + 64*32,  Ag + (size_t)64*K + k0);
    async_copy16(Bsl,          Bg + k0);
    async_copy16(Bsl + 64*32,  Bg + (size_t)64*K + k0);
    __syncthreads();
    bf16x8 a[4], b[4];
    #pragma unroll
    for(int i=0;i<4;i++) a[i] = *(const bf16x8*)&As[(wm*64 + i*16 + li)*32 + q*8];
    #pragma unroll
    for(int j=0;j<4;j++) b[j] = *(const bf16x8*)&Bs[(wn*64 + j*16 + li)*32 + q*8];
    #pragma unroll
    for(int i=0;i<4;i++)
      #pragma unroll
      for(int j=0;j<4;j++)
        acc[i][j] = __builtin_amdgcn_mfma_f32_16x16x32_bf16(a[i], b[j], acc[i][j], 0, 0, 0);
    __syncthreads();
  }
  float w2v[4], b1v[4];
  #pragma unroll
  for(int j=0;j<4;j++){ int gn = n0 + wn*64 + j*16 + li; w2v[j]=W2[gn]; b1v[j]=b1[gn]; }
  #pragma unroll
  for(int i=0;i<4;i++){
    #pragma unroll
    for(int r=0;r<4;r++){
      float s=0.f;
      #pragma unroll
      for(int j=0;j<4;j++){
        float v = acc[i][j][r] + b1v[j];
        v = v>0.f ? v : 0.f;
        s += v*w2v[j];
      }
      s += __shfl_xor(s,1); s += __shfl_xor(s,2); s += __shfl_xor(s,4); s += __shfl_xor(s,8);
      if(li==0) atomicAdd(&score_pre[m0 + wm*64 + i*16 + q*4 + r], s);
    }
  }
}

// fallback if ws can't hold W1b
__global__ __launch_bounds__(256) void attn_gemm_f32(const short* __restrict__ catT,
    const float* __restrict__ W1, const float* __restrict__ b1, const float* __restrict__ W2,
    float* __restrict__ score_pre){
  const int K = NN;
  int lane = threadIdx.x & 63;
  int wv   = threadIdx.x >> 6;
  int m0 = (blockIdx.x*4 + wv)*64;
  int n0 = blockIdx.y*64;
  int li = lane & 15, q = lane >> 4;
  const short* Ab = catT + (size_t)(m0+li)*K + q*8;
  const float* Bb = W1 + (size_t)(n0+li)*K + q*8;
  f32x4 acc[4][4];
  #pragma unroll
  for(int i=0;i<4;i++)
    #pragma unroll
    for(int j=0;j<4;j++) acc[i][j] = (f32x4){0.f,0.f,0.f,0.f};
  for(int k0=0;k0<K;k0+=32){
    bf16x8 a[4], b[4];
    #pragma unroll
    for(int i=0;i<4;i++) a[i] = *(const bf16x8*)(Ab + (size_t)i*16*K + k0);
    #pragma unroll
    for(int j=0;j<4;j++){
      const float* p = Bb + (size_t)j*16*K + k0;
      float4 f0 = *(const float4*)p;
      float4 f1 = *(const float4*)(p+4);
      bf16x8 t;
      t[0]=f2bf(f0.x); t[1]=f2bf(f0.y); t[2]=f2bf(f0.z); t[3]=f2bf(f0.w);
      t[4]=f2bf(f1.x); t[5]=f2bf(f1.y); t[6]=f2bf(f1.z); t[7]=f2bf(f1.w);
      b[j]=t;
    }
    #pragma unroll
    for(int i=0;i<4;i++)
      #pragma unroll
      for(int j=0;j<4;j++)
        acc[i][j] = __builtin_amdgcn_mfma_f32_16x16x32_bf16(a[i], b[j], acc[i][j], 0, 0, 0);
  }
  float w2v[4], b1v[4];
  #pragma unroll
  for(int j=0;j<4;j++){ int gn=n0+j*16+li; w2v[j]=W2[gn]; b1v[j]=b1[gn]; }
  #pragma unroll
  for(int i=0;i<4;i++){
    #pragma unroll
    for(int r=0;r<4;r++){
      float s=0.f;
      #pragma unroll
      for(int j=0;j<4;j++){
        float v = acc[i][j][r] + b1v[j];
        v = v>0.f ? v : 0.f;
        s += v*w2v[j];
      }
      s += __shfl_xor(s,1); s += __shfl_xor(s,2); s += __shfl_xor(s,4); s += __shfl_xor(s,8);
      if(li==0) atomicAdd(&score_pre[m0 + i*16 + q*4 + r], s);
    }
  }
}

// ---------------- score finalize ----------------
__global__ void k_score(const float* __restrict__ pre, const float* __restrict__ b2,
                        const float* __restrict__ center, const float* __restrict__ clsW,
                        float* __restrict__ sw){
  int d = blockIdx.x*256 + threadIdx.x;
  if(d>=DCATD) return;
  float sc = pre[d] + b2[0];
  sc = 1.f/(1.f+expf(-sc));
  sc -= center[d];
  #pragma unroll
  for(int o=0;o<10;o++) sw[d*10+o] = sc * clsW[(size_t)o*DCATD + d];
}

// ---------------- final ----------------
__global__ __launch_bounds__(64) void k_final(const float* __restrict__ x, const float* __restrict__ o1,
    const float* __restrict__ o2, const float* __restrict__ sw, const float* __restrict__ clsb,
    float* __restrict__ out){
  int i = blockIdx.x, l = threadIdx.x;
  float acc[10];
  #pragma unroll
  for(int o=0;o<10;o++) acc[o]=0.f;
  for(int d=l; d<DCATD; d+=64){
    float v = (d<FD) ? x[(size_t)i*FD + d]
            : (d<FD+HIDD) ? o1[(size_t)i*HIDD + d-FD]
            : o2[(size_t)i*HIDD + d-FD-HIDD];
    const float* s = sw + (size_t)d*10;
    #pragma unroll
    for(int o=0;o<10;o++) acc[o] += v*s[o];
  }
  #pragma unroll
  for(int o=0;o<10;o++){
    float t = acc[o];
    for(int off=32;off;off>>=1) t += __shfl_down(t,off);
    if(l==0) out[(size_t)i*10 + o] = t + clsb[o];
  }
}

extern "C" void kernel_launch(void* const* d_in, const int* in_sizes, int n_in,
                              void* d_out, int out_size, void* d_ws, size_t ws_size,
                              hipStream_t stream) {
  const float* x      = (const float*)d_in[0];
  const int*   ei     = (const int*)d_in[1];
  const float* eattr  = (const float*)d_in[2];
  const float* gn1_w  = (const float*)d_in[3];
  const float* gn1_b  = (const float*)d_in[4];
  const float* gn1_ms = (const float*)d_in[5];
  const float* gn2_w  = (const float*)d_in[6];
  const float* gn2_b  = (const float*)d_in[7];
  const float* gn2_ms = (const float*)d_in[8];
  const float* hg1_W  = (const float*)d_in[9];
  const float* hg1_att= (const float*)d_in[10];
  const float* hg1_b  = (const float*)d_in[11];
  const float* hg2_W  = (const float*)d_in[12];
  const float* hg2_att= (const float*)d_in[13];
  const float* hg2_b  = (const float*)d_in[14];
  const float* fc1_W  = (const float*)d_in[15];
  const float* fc1_b  = (const float*)d_in[16];
  const float* fc2_W  = (const float*)d_in[17];
  const float* fc2_b  = (const float*)d_in[18];
  const float* attn_W1= (const float*)d_in[19];
  const float* attn_b1= (const float*)d_in[20];
  const float* attn_W2= (const float*)d_in[21];
  const float* attn_b2= (const float*)d_in[22];
  const float* cls_W  = (const float*)d_in[23];
  const float* cls_b  = (const float*)d_in[24];
  const float* center = (const float*)d_in[25];
  float* out = (float*)d_out;

  const int* row = ei;
  const int* col = ei + NNZE;

  char* w = (char*)d_ws;
  size_t off = 0;
  auto alloc = [&](size_t bytes)->void*{
    off = (off + 255) & ~(size_t)255;
    void* p = w + off;
    off += bytes;
    return p;
  };
  float* xt    = (float*)alloc((size_t)NN*FD*4);
  float* ef    = (float*)alloc((size_t)NN*FD*4);     // later aliased as catT (bf16)
  float* h     = (float*)alloc((size_t)NN*FD*4);
  float* out1  = (float*)alloc((size_t)NN*HIDD*4);
  float* out2  = (float*)alloc((size_t)NN*HIDD*4);
  short* inb   = (short*)alloc((size_t)NN*FD*2);     // normalized bf16 (affdot out)
  short* hbf   = (short*)alloc((size_t)NN*FD*2);     // h bf16 (seg_gather dual out)
  short* wb1   = (short*)alloc((size_t)FD*FD*2);
  short* wb2   = (short*)alloc((size_t)FD*FD*2);
  short* fwb1  = (short*)alloc((size_t)HIDD*FD*2);
  short* fwb2  = (short*)alloc((size_t)HIDD*FD*2);
  int* cnt_col = (int*)alloc(NN*4);                  // adjacent to cnt_row (one memset)
  int* cnt_row = (int*)alloc(NN*4);
  int* col_off = (int*)alloc((NN+1)*4);
  int* row_off = (int*)alloc((NN+1)*4);
  int* col_cur = (int*)alloc(NN*4);
  int* row_cur = (int*)alloc(NN*4);
  int* ceids   = (int*)alloc(NNZE*4);
  int* reids   = (int*)alloc(NNZE*4);
  float* Bn    = (float*)alloc(NN*4);
  float* Dn    = (float*)alloc(NN*4);
  float* a_x   = (float*)alloc(NN*4);
  float* a_e   = (float*)alloc(NN*4);
  float* asm_  = (float*)alloc(NNZE*4);
  float* gsum  = (float*)alloc(FD*4);                // adjacent to gssq (one memset)
  float* gssq  = (float*)alloc(FD*4);
  float* gnA   = (float*)alloc(FD*4);
  float* gnB   = (float*)alloc(FD*4);
  float* wxr   = (float*)alloc(FD*4);
  float* we    = (float*)alloc(FD*4);
  float* score_pre = (float*)alloc(DCATD*4);
  float* sw    = (float*)alloc(DCATD*10*4);
  short* catT  = (short*)ef;   // alias: ef dead by the time catT is built
  size_t off_before_w1b = off;
  short* W1b   = (short*)alloc((size_t)NN*NN*2);
  bool use_w1b = (off <= ws_size);
  if(!use_w1b) off = off_before_w1b;
  (void)n_in; (void)in_sizes; (void)out_size;

  // ---- CSR build (4 dispatches + 1 memset) ----
  hipMemsetAsync(cnt_col, 0, 2*NN*4, stream);        // covers cnt_col + cnt_row
  k_hist<<<NNZE/256, 256, 0, stream>>>(row, col, cnt_row, cnt_col);
  k_scan2<<<2, 1024, 0, stream>>>(cnt_col, cnt_row, col_off, row_off, col_cur, row_cur, Bn, Dn);
  k_scatter<<<NNZE/256, 256, 0, stream>>>(row, col, col_cur, row_cur, ceids, reids);

  // ---- all weight conversions in one dispatch ----
  int nW1 = use_w1b ? (int)((size_t)NN*NN/2048) : 0;   // 32768 or 0
  k_cvt_all<<<nW1 + 864, 256, 0, stream>>>(nW1, attn_W1, W1b,
      hg1_W, wb1, hg2_W, wb2, fc1_W, fwb1, fc2_W, fwb2);

  for(int layer=0; layer<2; layer++){
    const float* src_feat = (layer==0) ? x : h;
    const float* gW   = (layer==0) ? gn1_w  : gn2_w;
    const float* gB   = (layer==0) ? gn1_b  : gn2_b;
    const float* gMS  = (layer==0) ? gn1_ms : gn2_ms;
    const float* hgW  = (layer==0) ? hg1_W  : hg2_W;
    const float* hgAtt= (layer==0) ? hg1_att: hg2_att;
    const float* hgB  = (layer==0) ? hg1_b  : hg2_b;
    const short* wbL  = (layer==0) ? wb1    : wb2;
    const short* fwbL = (layer==0) ? fwb1   : fwb2;
    const float* fcB  = (layer==0) ? fc1_b  : fc2_b;
    float* fout       = (layer==0) ? out1   : out2;

    hipMemsetAsync(gsum, 0, 2*FD*4, stream);         // covers gsum + gssq
    k_colstats<<<dim3(3,32), 256, 0, stream>>>(src_feat, gsum, gssq);
    k_watt<<<FD, 256, 0, stream>>>(hgW, hgAtt, gsum, gssq, gW, gB, gMS, gnA, gnB, wxr, we);
    k_matvec<<<NN, 64, 0, stream>>>(eattr, we, a_e);
    k_affdot<<<NN, 256, 0, stream>>>(src_feat, gnA, gnB, wxr, inb, a_x);
    gemm_lds<<<dim3(FD/128, NN/128), 256, 0, stream>>>(inb, wbL, xt, NN, FD, FD, nullptr, 1.f);
    k_softmax_seg<<<NN/4, 256, 0, stream>>>(col_off, ceids, row, a_x, a_e, asm_);
    k_seg_gather<<<NN, 192, 0, stream>>>(xt, col_off, ceids, row, asm_, Bn, nullptr, 1.f, ef, nullptr);
    k_seg_gather<<<NN, 192, 0, stream>>>(ef, row_off, reids, col, asm_, Dn, hgB, 0.01f, h, hbf);
    gemm_lds<<<dim3(HIDD/128, NN/128), 256, 0, stream>>>(hbf, fwbL, fout, NN, HIDD, FD, fcB, 0.01f);
  }

  // ---- attention over cat = [x, out1, out2] ----
  k_build_catT<<<dim3(NN/32, DCATD/32), dim3(32,8), 0, stream>>>(x, out1, out2, catT);
  hipMemsetAsync(score_pre, 0, DCATD*4, stream);
  if(use_w1b)
    attn_gemm_lds<<<768, 256, 0, stream>>>(catT, W1b, attn_b1, attn_W2, score_pre);
  else
    attn_gemm_f32<<<dim3(DCATD/256, NN/64), 256, 0, stream>>>(catT, attn_W1, attn_b1, attn_W2, score_pre);
  k_score<<<DCATD/256, 256, 0, stream>>>(score_pre, attn_b2, center, cls_W, sw);
  k_final<<<NN, 64, 0, stream>>>(x, out1, out2, sw, cls_b, out);
}